// Round 10
// baseline (417.206 us; speedup 1.0000x reference)
//
#include <hip/hip_runtime.h>
#include <hip/hip_bf16.h>

typedef __hip_bfloat16 bf16;
typedef __attribute__((ext_vector_type(8))) short bf16x8;
typedef __attribute__((ext_vector_type(4))) short short4v;
typedef __attribute__((ext_vector_type(4))) float f32x4;

#define BATCH 2
#define CH 64
#define NPIX 65536  // 256*256
#define HDIM 256
#define NLAYER 4
#define NGRP 8
#define NSLOT 512    // per-b know slots (= qkvg blocks per b)

// ---- workspace byte offsets ----
// feat is [b][px][c] (c-minor) bf16
#define OFS_FEAT   0ull          // 16777216 B
#define OFS_KSLOT  16777216ull   // 2 b x 512 slots x 4096 bf16 = 8388608 B
#define OFS_MEMBG  25165824ull   // 16384 B
#define OFS_FSUM   25182208ull   // 16384 B (strided x32)
#define OFS_SSUM   25198592ull   // 16384 B (2 ping x 2048 f)
#define OFS_BEFF   25214976ull   // 512 B
#define OFS_MEFFB  25215488ull   // 16384 B (bf16, GN-folded)
#define OFS_WFOLD  25231872ull   // 4 mats x 2 b x 4096 bf16 = 65536 B
#define OFS_BFOLD  25297408ull   // 4 mats x 2 b x 64 f32 = 2048 B
#define OFS_WTOUT  25299456ull   // 4608 B  ([o][k][c] f32)
#define OFS_WPB    25304064ull   // 32768 B (bf16)
#define OFS_WQTB   25336832ull   // 32768 B (bf16, transposed [e][c])
#define ZERO_BYTES 32768         // fsum + ssum (contiguous from OFS_FSUM)

__device__ __forceinline__ float sigmoidf_(float x){ return 1.0f/(1.0f+__expf(-x)); }

// f32 -> bf16 bits, round-to-nearest-even
__device__ __forceinline__ short f2bs(float x){
  unsigned u = __float_as_uint(x);
  u += 0x7fffu + ((u >> 16) & 1u);
  return (short)(u >> 16);
}
// bf16 bits -> f32
__device__ __forceinline__ float bs2f(short x){
  return __uint_as_float(((unsigned)(unsigned short)x) << 16);
}

__device__ __forceinline__ float waveReduce(float v){
  #pragma unroll
  for (int off=32; off; off>>=1) v += __shfl_xor(v, off, 64);
  return v;
}

// ---------- weight pre-convert (Wp, WqT, Wout only; GN-folded mats done per layer) ----------
__global__ void k_prepw(const float* __restrict__ Wout, const float* __restrict__ Wp,
                        const float* __restrict__ Wq,
                        float* __restrict__ wtout, short* __restrict__ Wpb,
                        short* __restrict__ Wqtb){
  int i = blockIdx.x*256 + threadIdx.x;
  if (i < 16384){
    Wpb[i] = f2bs(Wp[i]);
    int l = i >> 12, within = i & 4095;
    int e = within >> 6, c = within & 63;
    Wqtb[i] = f2bs(Wq[l*4096 + c*64 + e]);   // WqT[e][c] = Wq[c][e]
  }
  if (i < 1152){
    int o = i / 576, rem = i % 576;
    int k = rem >> 6, c = rem & 63;
    wtout[(o*9 + k)*64 + c] = Wout[o*576 + c*9 + k];
  }
}

// ---------- per-block group-stat reduction (conv_in); ssum entries strided x32 ----------
__device__ __forceinline__ void blockStats(const float* gs, const float* gq,
                                           float* ssum_b, int t){
  __shared__ float sacc[16];
  if (t < 16) sacc[t] = 0.f;
  __syncthreads();
  #pragma unroll
  for (int g=0; g<NGRP; g++){
    float s  = waveReduce(gs[g]);
    float sq = waveReduce(gq[g]);
    if ((t & 63) == 0){ atomicAdd(&sacc[g*2], s); atomicAdd(&sacc[g*2+1], sq); }
  }
  __syncthreads();
  if (t < 16) atomicAdd(&ssum_b[t*32], sacc[t]);
}

// ---------- conv3x3 2->64 + fused GN stats; feat out [px][c] bf16 ----------
__global__ void k_conv_in(const float* __restrict__ x, const float* __restrict__ w,
                          const float* __restrict__ bias,
                          short* __restrict__ feat, float* __restrict__ ssum){
  int b = blockIdx.y;
  int t = threadIdx.x;
  int n = blockIdx.x*256 + t;
  int y = n >> 8, xx = n & 255;
  float patch[18];
  int idx = 0;
  #pragma unroll
  for (int ci=0; ci<2; ci++)
    #pragma unroll
    for (int dy=-1; dy<=1; dy++)
      #pragma unroll
      for (int dx=-1; dx<=1; dx++){
        int yy = y+dy, xc = xx+dx;
        float v = 0.f;
        if (yy>=0 && yy<HDIM && xc>=0 && xc<HDIM)
          v = x[((b*2+ci)*HDIM + yy)*HDIM + xc];
        patch[idx++] = v;
      }
  float gs[NGRP], gq[NGRP];
  #pragma unroll
  for (int g=0; g<NGRP; g++){ gs[g]=0.f; gq[g]=0.f; }
  short* fb = feat + ((size_t)b*NPIX + n)*64;
  #pragma unroll
  for (int c4=0; c4<16; c4++){
    short4v sv;
    #pragma unroll
    for (int j=0;j<4;j++){
      int o = c4*4 + j;
      float acc = bias[o];
      #pragma unroll
      for (int k=0; k<18; k++) acc += w[o*18+k]*patch[k];
      sv[j] = f2bs(acc);
      gs[o>>3] += acc; gq[o>>3] += acc*acc;
    }
    *(short4v*)(fb + c4*4) = sv;
  }
  blockStats(gs, gq, ssum + b*512, t);
}

// ---------- GN coefficient compute (ssum strided) ----------
__device__ __forceinline__ void gnCoef(const float* __restrict__ ssum_l, int b, int t,
                                       const float* __restrict__ gammaP,
                                       const float* __restrict__ betaP, int l,
                                       float* s_gnA, float* s_gnB){
  if (t < 64){
    int g = t >> 3;
    const float inv = 1.0f/(8.0f*NPIX);
    float s  = ssum_l[(b*16 + g*2)*32];
    float sq = ssum_l[(b*16 + g*2 + 1)*32];
    float mu = s*inv;
    float var = sq*inv - mu*mu;
    float rstd = rsqrtf(var + 1e-5f);
    float A = rstd * gammaP[l*64 + t];
    s_gnA[t] = A;
    s_gnB[t] = betaP[l*64 + t] - mu * A;
  }
}

// ---------- fold GN into k/i/v/f weights; block = (mat, b) ----------
__global__ __launch_bounds__(256) void k_fold(
    const float* __restrict__ Wk, const float* __restrict__ Wv,
    const float* __restrict__ Wg,
    const float* __restrict__ bkP, const float* __restrict__ bvP,
    const float* __restrict__ bgP,
    const float* __restrict__ gammaP, const float* __restrict__ betaP,
    const float* __restrict__ ssum_l, int l,
    short* __restrict__ wfold, float* __restrict__ bfold)
{
  int mat = blockIdx.x & 3;   // 0=k 1=i 2=v 3=f
  int b = blockIdx.x >> 2;
  int t = threadIdx.x;
  __shared__ float sA[64], sB[64];
  __shared__ float sred[256];

  gnCoef(ssum_l, b, t, gammaP, betaP, l, sA, sB);
  __syncthreads();

  const float* Wsrc;
  const float* bsrc;
  if (mat == 0){ Wsrc = Wk + l*4096;        bsrc = bkP + l*64; }
  else if (mat == 1){ Wsrc = Wg + l*8192 + 4096; bsrc = bgP + l*128 + 64; }
  else if (mat == 2){ Wsrc = Wv + l*4096;   bsrc = bvP + l*64; }
  else { Wsrc = Wg + l*8192;                bsrc = bgP + l*128; }
  short* Wdst = wfold + mat*8192 + b*4096;
  float* bdst = bfold + mat*128 + b*64;

  #pragma unroll
  for (int idx = t; idx < 4096; idx += 256){
    int c = idx & 63;
    Wdst[idx] = f2bs(Wsrc[idx] * sA[c]);
  }
  // bias' = b + W.B : thread (o, cq) computes 16-c partial
  int o = t & 63, cq = t >> 6;
  float p = 0.f;
  #pragma unroll
  for (int cc=0; cc<16; cc++){
    int c = cq*16 + cc;
    p += Wsrc[o*64 + c] * sB[c];
  }
  sred[t] = p;
  __syncthreads();
  if (t < 64)
    bdst[t] = bsrc[t] + sred[t] + sred[64+t] + sred[128+t] + sred[192+t];
}

// ---------- MFMA: k/i/v/f GEMMs (GN pre-folded) + fused knowledge; 128 px/block ----------
__global__ __launch_bounds__(256,3) void k_qkvg_know(
    const short* __restrict__ feat,
    const short* __restrict__ wfold, const float* __restrict__ bfold,
    short* __restrict__ kslot, float* __restrict__ f_sum)
{
  int b = blockIdx.y;
  int n0 = blockIdx.x * 128;
  int t = threadIdx.x;
  int w = t >> 6;
  int lane = t & 63;
  int m = lane & 15;
  int quad = lane >> 4;
  int rowbase = w*16;

  __shared__ short s_buf[17408];        // s_kg + s_v
  short* s_kg = s_buf;                   // [c][px] stride 136
  short* s_v  = s_buf + 8704;

  const short* wkf = wfold + b*4096;
  const short* wif = wfold + 8192  + b*4096;
  const short* wvf = wfold + 16384 + b*4096;
  const short* wff = wfold + 24576 + b*4096;

  float bkv[4], biv[4], bvv[4], bfv[4], fs[4];
  #pragma unroll
  for (int r=0;r<4;r++){
    int row = rowbase + quad*4 + r;
    bkv[r] = bfold[b*64 + row];
    biv[r] = bfold[128 + b*64 + row];
    bvv[r] = bfold[256 + b*64 + row];
    bfv[r] = bfold[384 + b*64 + row];
    fs[r] = 0.f;
  }
  f32x4 z4 = {0.f,0.f,0.f,0.f};
  f32x4 accn[4];
  #pragma unroll
  for (int dt=0;dt<4;dt++) accn[dt] = z4;

  // ---- B-fragments direct from global (L1-hot tile) ----
  const short* fbase = feat + ((size_t)b*NPIX + n0)*64;
  bf16x8 Bf[2][8];
  #pragma unroll
  for (int kc=0;kc<2;kc++)
    #pragma unroll
    for (int nt=0;nt<8;nt++)
      Bf[kc][nt] = *(const bf16x8*)(fbase + (nt*16+m)*64 + kc*32 + quad*8);

  // ---- k & i -> kg ----
  {
    bf16x8 Ak[2], Ai[2];
    #pragma unroll
    for (int kc=0;kc<2;kc++){
      Ak[kc] = *(const bf16x8*)&wkf[(rowbase+m)*64 + kc*32 + quad*8];
      Ai[kc] = *(const bf16x8*)&wif[(rowbase+m)*64 + kc*32 + quad*8];
    }
    #pragma unroll
    for (int half=0; half<2; half++){
      f32x4 acck[4], acci[4];
      #pragma unroll
      for (int q4=0;q4<4;q4++){ acck[q4]=z4; acci[q4]=z4; }
      #pragma unroll
      for (int kc=0;kc<2;kc++)
        #pragma unroll
        for (int q4=0;q4<4;q4++){
          acck[q4] = __builtin_amdgcn_mfma_f32_16x16x32_bf16(Ak[kc], Bf[kc][half*4+q4], acck[q4], 0,0,0);
          acci[q4] = __builtin_amdgcn_mfma_f32_16x16x32_bf16(Ai[kc], Bf[kc][half*4+q4], acci[q4], 0,0,0);
        }
      #pragma unroll
      for (int q4=0;q4<4;q4++){
        int nt = half*4+q4;
        #pragma unroll
        for (int r=0;r<4;r++){
          int row = rowbase + quad*4 + r;
          float kv = acck[q4][r] + bkv[r];
          float iv = acci[q4][r] + biv[r];
          s_kg[row*136 + nt*16 + m] = f2bs(kv * sigmoidf_(iv));
        }
      }
    }
  }
  // ---- v ----
  {
    bf16x8 Av[2];
    #pragma unroll
    for (int kc=0;kc<2;kc++)
      Av[kc] = *(const bf16x8*)&wvf[(rowbase+m)*64 + kc*32 + quad*8];
    #pragma unroll
    for (int half=0; half<2; half++){
      f32x4 accv[4];
      #pragma unroll
      for (int q4=0;q4<4;q4++) accv[q4]=z4;
      #pragma unroll
      for (int kc=0;kc<2;kc++)
        #pragma unroll
        for (int q4=0;q4<4;q4++)
          accv[q4] = __builtin_amdgcn_mfma_f32_16x16x32_bf16(Av[kc], Bf[kc][half*4+q4], accv[q4], 0,0,0);
      #pragma unroll
      for (int q4=0;q4<4;q4++){
        int nt = half*4+q4;
        #pragma unroll
        for (int r=0;r<4;r++){
          int row = rowbase + quad*4 + r;
          s_v[row*136 + nt*16 + m] = f2bs(accv[q4][r] + bvv[r]);
        }
      }
    }
  }
  // ---- f -> fs ----
  {
    bf16x8 Af[2];
    #pragma unroll
    for (int kc=0;kc<2;kc++)
      Af[kc] = *(const bf16x8*)&wff[(rowbase+m)*64 + kc*32 + quad*8];
    #pragma unroll
    for (int half=0; half<2; half++){
      f32x4 accf[4];
      #pragma unroll
      for (int q4=0;q4<4;q4++) accf[q4]=z4;
      #pragma unroll
      for (int kc=0;kc<2;kc++)
        #pragma unroll
        for (int q4=0;q4<4;q4++)
          accf[q4] = __builtin_amdgcn_mfma_f32_16x16x32_bf16(Af[kc], Bf[kc][half*4+q4], accf[q4], 0,0,0);
      #pragma unroll
      for (int q4=0;q4<4;q4++)
        #pragma unroll
        for (int r=0;r<4;r++)
          fs[r] += sigmoidf_(accf[q4][r] + bfv[r]);
    }
  }
  __syncthreads();   // s_kg/s_v complete before knowledge reads

  // ---- knowledge ----
  #pragma unroll
  for (int kc4=0; kc4<4; kc4++){
    bf16x8 a = *(const bf16x8*)&s_kg[(rowbase + m)*136 + kc4*32 + quad*8];
    #pragma unroll
    for (int dt=0; dt<4; dt++){
      bf16x8 bv8 = *(const bf16x8*)&s_v[(dt*16 + m)*136 + kc4*32 + quad*8];
      accn[dt] = __builtin_amdgcn_mfma_f32_16x16x32_bf16(a, bv8, accn[dt], 0,0,0);
    }
  }

  // ---- f_sum (strided entries) ----
  #pragma unroll
  for (int off=1; off<16; off<<=1)
    #pragma unroll
    for (int r=0;r<4;r++) fs[r] += __shfl_xor(fs[r], off, 64);
  if (m == 0){
    #pragma unroll
    for (int r=0;r<4;r++)
      atomicAdd(&f_sum[(b*64 + rowbase + quad*4 + r)*32], fs[r]);
  }
  // ---- know contribution -> per-block slot (bf16, coalesced stores) ----
  short* kr = kslot + ((size_t)b*NSLOT + blockIdx.x)*4096;
  #pragma unroll
  for (int dt=0;dt<4;dt++)
    #pragma unroll
    for (int r=0;r<4;r++)
      kr[(rowbase + quad*4 + r)*64 + dt*16 + m] = f2bs(accn[dt][r]);
}

// ---------- parallel know-slot reduction + mem update; 32 blocks per b ----------
__global__ __launch_bounds__(256) void k_memreduce(
    const short* __restrict__ kslot, const float* __restrict__ f_sum,
    const float* __restrict__ hidden_in, int l,
    float* __restrict__ hidden_out, short* __restrict__ membG)
{
  int b = blockIdx.y;
  int t = threadIdx.x;
  int e = t & 127;
  int half = t >> 7;
  int cd = blockIdx.x*128 + e;

  const short* base = kslot + ((size_t)b*NSLOT + half*256)*4096 + cd;
  float s = 0.f;
  #pragma unroll 16
  for (int sl=0; sl<256; sl++) s += bs2f(base[(size_t)sl*4096]);

  __shared__ float red[128];
  if (half) red[e] = s;
  __syncthreads();
  if (!half){
    const float invN = 1.0f/(float)NPIX;
    float kn = (s + red[e]) * invN;
    float fmean = f_sum[(b*64 + (cd>>6))*32] * invN;
    float pm = hidden_in[(size_t)(b*NLAYER+l)*4096 + cd];
    float nm = fmean*pm + kn;
    hidden_out[(size_t)(b*NLAYER+l)*4096 + cd] = nm;
    membG[b*4096 + cd] = f2bs(nm);
  }
}

// ---------- Meff + beff via MFMA, with GN folded into Meff'/beff' ----------
__global__ __launch_bounds__(256) void k_meff(
    const short* __restrict__ membG, float* __restrict__ f_sum,
    const short* __restrict__ Wpb, const short* __restrict__ Wqtb,
    const float* __restrict__ bqP, const float* __restrict__ bpP,
    const float* __restrict__ gammaP, const float* __restrict__ betaP,
    const float* __restrict__ ssum_l,
    int l, short* __restrict__ Meffb, float* __restrict__ beff,
    float* __restrict__ ssum_next)
{
  int b = blockIdx.x;
  int t = threadIdx.x;
  int w = t >> 6;
  int lane = t & 63;
  int m = lane & 15;
  int quad = lane >> 4;

  __shared__ short s_memb[64*72];  // mem[c][d] bf16, stride 72
  __shared__ short s_mfb[64*72];   // mf[o][c] bf16, stride 72
  __shared__ float s_bq[64], s_A[64], s_B[64];

  gnCoef(ssum_l, b, t, gammaP, betaP, l, s_A, s_B);
  if (t < 64) s_bq[t] = bqP[l*64 + t];

  #pragma unroll
  for (int i=0;i<16;i++){
    int cd = t + i*256;
    int c = cd >> 6, d = cd & 63;
    s_memb[c*72 + d] = membG[b*4096 + cd];
  }
  __syncthreads();
  if (t < 64) f_sum[(b*64 + t)*32] = 0.f;
  if (t < 16) ssum_next[(b*16 + t)*32] = 0.f;

  f32x4 z4 = {0.f,0.f,0.f,0.f};

  // ---- GEMM1: mf[o][c] = sum_d Wp[o][d]*mem[c][d] ----
  bf16x8 Ap[2];
  #pragma unroll
  for (int kc=0;kc<2;kc++)
    Ap[kc] = *(const bf16x8*)&Wpb[l*4096 + (w*16+m)*64 + kc*32 + quad*8];

  float be[4];
  #pragma unroll
  for (int r=0;r<4;r++) be[r] = 0.f;

  #pragma unroll
  for (int ct=0; ct<4; ct++){
    f32x4 a = z4;
    #pragma unroll
    for (int kc=0;kc<2;kc++){
      bf16x8 Bm = *(const bf16x8*)&s_memb[(ct*16+m)*72 + kc*32 + quad*8];
      a = __builtin_amdgcn_mfma_f32_16x16x32_bf16(Ap[kc], Bm, a, 0,0,0);
    }
    int c = ct*16 + m;
    #pragma unroll
    for (int r=0;r<4;r++){
      int o = w*16 + quad*4 + r;
      s_mfb[o*72 + c] = f2bs(a[r]);
      be[r] += a[r] * s_bq[c];    // bq contribution
    }
  }
  __syncthreads();

  // ---- GEMM2: Meff'[o][e] = 0.125*(mf.WqT)[o][e]*A[e];  bee = (mf.WqT).B ----
  bf16x8 Am2[2];
  #pragma unroll
  for (int kc=0;kc<2;kc++)
    Am2[kc] = *(const bf16x8*)&s_mfb[(w*16+m)*72 + kc*32 + quad*8];
  #pragma unroll
  for (int et=0; et<4; et++){
    f32x4 a = z4;
    #pragma unroll
    for (int kc=0;kc<2;kc++){
      bf16x8 Bq = *(const bf16x8*)&Wqtb[l*4096 + (et*16+m)*64 + kc*32 + quad*8];
      a = __builtin_amdgcn_mfma_f32_16x16x32_bf16(Am2[kc], Bq, a, 0,0,0);
    }
    int e = et*16 + m;
    #pragma unroll
    for (int r=0;r<4;r++){
      int o = w*16 + quad*4 + r;
      Meffb[(size_t)b*4096 + o*64 + e] = f2bs(0.125f*a[r]*s_A[e]);
      be[r] += a[r] * s_B[e];     // B contribution (same 0.125 scale applied below)
    }
  }
  #pragma unroll
  for (int off=1; off<16; off<<=1)
    #pragma unroll
    for (int r=0;r<4;r++) be[r] += __shfl_xor(be[r], off, 64);
  if (m == 0){
    #pragma unroll
    for (int r=0;r<4;r++){
      int o = w*16 + quad*4 + r;
      beff[b*64 + o] = bpP[l*64 + o] + 0.125f*be[r];
    }
  }
}

// ---------- retrieval+proj+residual (GN pre-folded) + next-layer GN stats ----------
__global__ __launch_bounds__(256,3) void k_retrproj(
    const short* __restrict__ Meffb, const float* __restrict__ beff,
    short* __restrict__ feat, float* __restrict__ ssum_next)
{
  int b = blockIdx.y;
  int n0 = blockIdx.x * 128;
  int t = threadIdx.x;
  int w = t >> 6;
  int lane = t & 63;
  int m = lane & 15;
  int quad = lane >> 4;

  __shared__ float s_out[128*68];   // 34816 B
  __shared__ float s_beff[64];
  __shared__ float s_sacc[16];

  if (t < 64) s_beff[t] = beff[b*64 + t];
  if (t < 16) s_sacc[t] = 0.f;

  short* fbase = feat + ((size_t)b*NPIX + n0)*64;

  // B-fragments direct from global
  bf16x8 Bf[2][8];
  #pragma unroll
  for (int kc=0;kc<2;kc++)
    #pragma unroll
    for (int nt=0;nt<8;nt++)
      Bf[kc][nt] = *(const bf16x8*)(fbase + (nt*16+m)*64 + kc*32 + quad*8);

  bf16x8 Am[2];
  #pragma unroll
  for (int kc=0;kc<2;kc++)
    Am[kc] = *(const bf16x8*)&Meffb[(size_t)b*4096 + (w*16 + m)*64 + kc*32 + quad*8];

  f32x4 acc[8];
  f32x4 z4 = {0.f,0.f,0.f,0.f};
  #pragma unroll
  for (int nt=0;nt<8;nt++) acc[nt]=z4;
  #pragma unroll
  for (int kc=0;kc<2;kc++)
    #pragma unroll
    for (int nt=0;nt<8;nt++)
      acc[nt] = __builtin_amdgcn_mfma_f32_16x16x32_bf16(Am[kc], Bf[kc][nt], acc[nt], 0,0,0);

  // transpose retrieval output into [px][c]
  #pragma unroll
  for (int nt=0;nt<8;nt++)
    #pragma unroll
    for (int r=0;r<4;r++)
      s_out[(nt*16+m)*68 + w*16 + quad*4 + r] = acc[nt][r];
  __syncthreads();

  // writeback (feat re-read is cache-hot) + next-layer GN stats
  float gsv = 0.f, gqv = 0.f;
  int c8 = (t & 7)*8;
  #pragma unroll
  for (int i=0;i<4;i++){
    int chunk = t + i*256;
    int px = chunk >> 3;
    short* fp = fbase + px*64 + c8;
    bf16x8 rv = *(const bf16x8*)fp;
    f32x4 o1 = *(const f32x4*)&s_out[px*68 + c8];
    f32x4 o2 = *(const f32x4*)&s_out[px*68 + c8 + 4];
    short4v r1, r2;
    #pragma unroll
    for (int j=0;j<4;j++){
      float o = bs2f(rv[j]) + o1[j] + s_beff[c8+j];
      r1[j] = f2bs(o);
      gsv += o; gqv += o*o;
    }
    #pragma unroll
    for (int j=0;j<4;j++){
      float o = bs2f(rv[j+4]) + o2[j] + s_beff[c8+4+j];
      r2[j] = f2bs(o);
      gsv += o; gqv += o*o;
    }
    *(short4v*)fp = r1;
    *(short4v*)(fp+4) = r2;
  }
  // reduce the 8 lanes sharing a group (equal lane&7): xor bits 3,4,5
  gsv += __shfl_xor(gsv, 8, 64);  gqv += __shfl_xor(gqv, 8, 64);
  gsv += __shfl_xor(gsv, 16, 64); gqv += __shfl_xor(gqv, 16, 64);
  gsv += __shfl_xor(gsv, 32, 64); gqv += __shfl_xor(gqv, 32, 64);
  if ((lane & 56) == 0){
    int g = lane & 7;
    atomicAdd(&s_sacc[g*2], gsv);
    atomicAdd(&s_sacc[g*2+1], gqv);
  }
  __syncthreads();
  if (t < 16) atomicAdd(&ssum_next[(b*16 + t)*32], s_sacc[t]);
}

// ---------- conv3x3 64->2 + residual; feat [px][c] bf16, weights [o][k][c] ----------
__global__ void k_conv_out(const short* __restrict__ feat, const float* __restrict__ wt,
                           const float* __restrict__ bias,
                           const float* __restrict__ xin, float* __restrict__ out){
  int b = blockIdx.y;
  int y = blockIdx.x;
  int xx = threadIdx.x;
  float acc0 = bias[0], acc1 = bias[1];
  #pragma unroll
  for (int dy=-1; dy<=1; dy++){
    int yy = y + dy;
    if (yy < 0 || yy >= HDIM) continue;
    #pragma unroll
    for (int dx=-1; dx<=1; dx++){
      int xc = xx + dx;
      if (xc >= 0 && xc < HDIM){
        const short* fp = feat + ((size_t)b*NPIX + yy*HDIM + xc)*64;
        const float* w0 = wt + ((0*3 + dy+1)*3 + dx+1)*64;
        const float* w1 = wt + ((1*3 + dy+1)*3 + dx+1)*64;
        #pragma unroll
        for (int c8=0;c8<8;c8++){
          bf16x8 fv = *(const bf16x8*)(fp + c8*8);
          f32x4 w0a = *(const f32x4*)(w0 + c8*8);
          f32x4 w0b = *(const f32x4*)(w0 + c8*8 + 4);
          f32x4 w1a = *(const f32x4*)(w1 + c8*8);
          f32x4 w1b = *(const f32x4*)(w1 + c8*8 + 4);
          #pragma unroll
          for (int j=0;j<4;j++){
            float fa = bs2f(fv[j]), fb2 = bs2f(fv[j+4]);
            acc0 += fa*w0a[j] + fb2*w0b[j];
            acc1 += fa*w1a[j] + fb2*w1b[j];
          }
        }
      }
    }
  }
  size_t p0 = (size_t)(b*2+0)*NPIX + y*HDIM + xx;
  size_t p1 = (size_t)(b*2+1)*NPIX + y*HDIM + xx;
  out[p0] = acc0 + xin[p0];
  out[p1] = acc1 + xin[p1];
}

extern "C" void kernel_launch(void* const* d_in, const int* in_sizes, int n_in,
                              void* d_out, int out_size, void* d_ws, size_t ws_size,
                              hipStream_t stream){
  char* ws = (char*)d_ws;
  short* feat  = (short*)(ws + OFS_FEAT);
  short* kslot = (short*)(ws + OFS_KSLOT);
  short* membg = (short*)(ws + OFS_MEMBG);
  float* fsum  = (float*)(ws + OFS_FSUM);
  float* ssum  = (float*)(ws + OFS_SSUM);   // 2 ping buffers of 1024 floats
  float* beff  = (float*)(ws + OFS_BEFF);
  short* meffb = (short*)(ws + OFS_MEFFB);
  short* wfold = (short*)(ws + OFS_WFOLD);
  float* bfold = (float*)(ws + OFS_BFOLD);
  float* wtout = (float*)(ws + OFS_WTOUT);
  short* wpb   = (short*)(ws + OFS_WPB);
  short* wqtb  = (short*)(ws + OFS_WQTB);

  const float* x      = (const float*)d_in[0];
  const float* hidden = (const float*)d_in[1];
  const float* W_in   = (const float*)d_in[2];
  const float* b_in   = (const float*)d_in[3];
  const float* gamma  = (const float*)d_in[4];
  const float* beta   = (const float*)d_in[5];
  const float* Wq     = (const float*)d_in[6];
  const float* bq     = (const float*)d_in[7];
  const float* Wk     = (const float*)d_in[8];
  const float* bk     = (const float*)d_in[9];
  const float* Wv     = (const float*)d_in[10];
  const float* bv     = (const float*)d_in[11];
  const float* Wg     = (const float*)d_in[12];
  const float* bg     = (const float*)d_in[13];
  const float* Wp     = (const float*)d_in[14];
  const float* bp     = (const float*)d_in[15];
  const float* W_out  = (const float*)d_in[16];
  const float* b_out  = (const float*)d_in[17];

  float* out        = (float*)d_out;
  float* hidden_out = out + BATCH*2*NPIX;

  hipMemsetAsync(ws + OFS_FSUM, 0, ZERO_BYTES, stream);
  k_prepw<<<dim3(64), dim3(256), 0, stream>>>(W_out, Wp, Wq, wtout, wpb, wqtb);
  k_conv_in<<<dim3(HDIM, BATCH), dim3(256), 0, stream>>>(x, W_in, b_in, feat, ssum);

  for (int l=0; l<NLAYER; l++){
    float* ssum_l = ssum + (l & 1)*1024;
    float* ssum_n = ssum + ((l+1) & 1)*1024;
    k_fold<<<dim3(8), dim3(256), 0, stream>>>(
        Wk, Wv, Wg, bk, bv, bg, gamma, beta, ssum_l, l, wfold, bfold);
    k_qkvg_know<<<dim3(NPIX/128, BATCH), dim3(256), 0, stream>>>(
        feat, wfold, bfold, kslot, fsum);
    k_memreduce<<<dim3(32, BATCH), dim3(256), 0, stream>>>(
        kslot, fsum, hidden, l, hidden_out, membg);
    k_meff<<<dim3(BATCH), dim3(256), 0, stream>>>(
        membg, fsum, wpb, wqtb, bq, bp, gamma, beta, ssum_l, l, meffb, beff, ssum_n);
    k_retrproj<<<dim3(NPIX/128, BATCH), dim3(256), 0, stream>>>(
        meffb, beff, feat, ssum_n);
  }

  k_conv_out<<<dim3(HDIM, BATCH), dim3(256), 0, stream>>>(feat, wtout, b_out, x, out);
}

// Round 11
// 372.365 us; speedup vs baseline: 1.1204x; 1.1204x over previous
//
#include <hip/hip_runtime.h>
#include <hip/hip_bf16.h>

typedef __hip_bfloat16 bf16;
typedef __attribute__((ext_vector_type(8))) short bf16x8;
typedef __attribute__((ext_vector_type(4))) short short4v;
typedef __attribute__((ext_vector_type(4))) float f32x4;

#define BATCH 2
#define CH 64
#define NPIX 65536  // 256*256
#define HDIM 256
#define NLAYER 4
#define NGRP 8
#define NSLOT 512    // per-b know slots (= qkvg blocks per b)

// ---- workspace byte offsets ----
// feat is [b][px][c] (c-minor) bf16
#define OFS_FEAT   0ull          // 16777216 B
#define OFS_KSLOT  16777216ull   // 2 b x 512 slots x 4096 bf16 = 8388608 B
#define OFS_MEMBG  25165824ull   // 16384 B
#define OFS_FSUM   25182208ull   // 16384 B (strided x32)
#define OFS_SSUM   25198592ull   // 16384 B (2 ping x 2048 f)
#define OFS_WKB    25214976ull   // 32768 B
#define OFS_WVB    25247744ull   // 32768 B
#define OFS_WGB    25280512ull   // 65536 B
#define OFS_WTOUT  25346048ull   // 4608 B  ([o][k][c] f32)
#define OFS_WPB    25350656ull   // 32768 B (bf16)
#define OFS_WQTB   25383424ull   // 32768 B (bf16, transposed [e][c])
#define ZERO_BYTES 32768         // fsum + ssum (contiguous from OFS_FSUM)

__device__ __forceinline__ float sigmoidf_(float x){ return 1.0f/(1.0f+__expf(-x)); }

// f32 -> bf16 bits, round-to-nearest-even
__device__ __forceinline__ short f2bs(float x){
  unsigned u = __float_as_uint(x);
  u += 0x7fffu + ((u >> 16) & 1u);
  return (short)(u >> 16);
}
// bf16 bits -> f32
__device__ __forceinline__ float bs2f(short x){
  return __uint_as_float(((unsigned)(unsigned short)x) << 16);
}

__device__ __forceinline__ float waveReduce(float v){
  #pragma unroll
  for (int off=32; off; off>>=1) v += __shfl_xor(v, off, 64);
  return v;
}

// ---------- weight pre-convert ----------
__global__ void k_prepw(const float* __restrict__ Wk, const float* __restrict__ Wv,
                        const float* __restrict__ Wg, const float* __restrict__ Wout,
                        const float* __restrict__ Wp, const float* __restrict__ Wq,
                        short* __restrict__ Wkb, short* __restrict__ Wvb,
                        short* __restrict__ Wgb, float* __restrict__ wtout,
                        short* __restrict__ Wpb, short* __restrict__ Wqtb){
  int i = blockIdx.x*256 + threadIdx.x;
  if (i < 16384){
    Wkb[i] = f2bs(Wk[i]);
    Wvb[i] = f2bs(Wv[i]);
    Wpb[i] = f2bs(Wp[i]);
    int l = i >> 12, within = i & 4095;
    int e = within >> 6, c = within & 63;
    Wqtb[i] = f2bs(Wq[l*4096 + c*64 + e]);   // WqT[e][c] = Wq[c][e]
  }
  if (i < 32768) Wgb[i] = f2bs(Wg[i]);
  if (i < 1152){
    int o = i / 576, rem = i % 576;
    int k = rem >> 6, c = rem & 63;
    wtout[(o*9 + k)*64 + c] = Wout[o*576 + c*9 + k];
  }
}

// ---------- per-block group-stat reduction (conv_in); ssum entries strided x32 ----------
__device__ __forceinline__ void blockStats(const float* gs, const float* gq,
                                           float* ssum_b, int t){
  __shared__ float sacc[16];
  if (t < 16) sacc[t] = 0.f;
  __syncthreads();
  #pragma unroll
  for (int g=0; g<NGRP; g++){
    float s  = waveReduce(gs[g]);
    float sq = waveReduce(gq[g]);
    if ((t & 63) == 0){ atomicAdd(&sacc[g*2], s); atomicAdd(&sacc[g*2+1], sq); }
  }
  __syncthreads();
  if (t < 16) atomicAdd(&ssum_b[t*32], sacc[t]);
}

// ---------- conv3x3 2->64 + fused GN stats; feat out [px][c] bf16 ----------
__global__ void k_conv_in(const float* __restrict__ x, const float* __restrict__ w,
                          const float* __restrict__ bias,
                          short* __restrict__ feat, float* __restrict__ ssum){
  int b = blockIdx.y;
  int t = threadIdx.x;
  int n = blockIdx.x*256 + t;
  int y = n >> 8, xx = n & 255;
  float patch[18];
  int idx = 0;
  #pragma unroll
  for (int ci=0; ci<2; ci++)
    #pragma unroll
    for (int dy=-1; dy<=1; dy++)
      #pragma unroll
      for (int dx=-1; dx<=1; dx++){
        int yy = y+dy, xc = xx+dx;
        float v = 0.f;
        if (yy>=0 && yy<HDIM && xc>=0 && xc<HDIM)
          v = x[((b*2+ci)*HDIM + yy)*HDIM + xc];
        patch[idx++] = v;
      }
  float gs[NGRP], gq[NGRP];
  #pragma unroll
  for (int g=0; g<NGRP; g++){ gs[g]=0.f; gq[g]=0.f; }
  short* fb = feat + ((size_t)b*NPIX + n)*64;
  #pragma unroll
  for (int c4=0; c4<16; c4++){
    short4v sv;
    #pragma unroll
    for (int j=0;j<4;j++){
      int o = c4*4 + j;
      float acc = bias[o];
      #pragma unroll
      for (int k=0; k<18; k++) acc += w[o*18+k]*patch[k];
      sv[j] = f2bs(acc);
      gs[o>>3] += acc; gq[o>>3] += acc*acc;
    }
    *(short4v*)(fb + c4*4) = sv;
  }
  blockStats(gs, gq, ssum + b*512, t);
}

// ---------- GN coefficient compute (ssum strided) ----------
__device__ __forceinline__ void gnCoef(const float* __restrict__ ssum_l, int b, int t,
                                       const float* __restrict__ gammaP,
                                       const float* __restrict__ betaP, int l,
                                       float* s_gnA, float* s_gnB){
  if (t < 64){
    int g = t >> 3;
    const float inv = 1.0f/(8.0f*NPIX);
    float s  = ssum_l[(b*16 + g*2)*32];
    float sq = ssum_l[(b*16 + g*2 + 1)*32];
    float mu = s*inv;
    float var = sq*inv - mu*mu;
    float rstd = rsqrtf(var + 1e-5f);
    float A = rstd * gammaP[l*64 + t];
    s_gnA[t] = A;
    s_gnB[t] = betaP[l*64 + t] - mu * A;
  }
}

// ---------- MFMA: GN + k/i/v/f GEMMs + fused knowledge; 128 px per block ----------
__global__ __launch_bounds__(256,3) void k_qkvg_know(
    const short* __restrict__ feat, const float* __restrict__ ssum_l,
    const float* __restrict__ gammaP, const float* __restrict__ betaP,
    const short* __restrict__ Wkb, const float* __restrict__ bkP,
    const short* __restrict__ Wvb, const float* __restrict__ bvP,
    const short* __restrict__ Wgb, const float* __restrict__ bgP,
    int l, short* __restrict__ kslot, float* __restrict__ f_sum)
{
  int b = blockIdx.y;
  int n0 = blockIdx.x * 128;
  int t = threadIdx.x;
  int w = t >> 6;
  int lane = t & 63;
  int m = lane & 15;
  int quad = lane >> 4;
  int rowbase = w*16;

  __shared__ short s_buf[17408];        // 34816 B; s_kg+s_v, aliased by s_xn
  short* s_kg = s_buf;                   // [c][px] stride 136
  short* s_v  = s_buf + 8704;
  short* s_xn = s_buf;                   // [px][c] stride 72 (9216 shorts)
  __shared__ float s_gnA[64], s_gnB[64];

  gnCoef(ssum_l, b, t, gammaP, betaP, l, s_gnA, s_gnB);

  float bkv[4], biv[4], bvv[4], bfv[4], fs[4];
  #pragma unroll
  for (int r=0;r<4;r++){
    int row = rowbase + quad*4 + r;
    bkv[r] = bkP[l*64 + row];
    biv[r] = bgP[l*128 + 64 + row];
    bvv[r] = bvP[l*64 + row];
    bfv[r] = bgP[l*128 + row];
    fs[r] = 0.f;
  }
  f32x4 z4 = {0.f,0.f,0.f,0.f};
  f32x4 accn[4];
  #pragma unroll
  for (int dt=0;dt<4;dt++) accn[dt] = z4;

  __syncthreads();

  // ---- stage GN'd tile (bf16 global -> bf16 LDS) ----
  const short* fbase = feat + ((size_t)b*NPIX + n0)*64;
  #pragma unroll
  for (int i=0;i<4;i++){
    int chunk = t + i*256;               // 1024 chunks of 8 shorts
    int px = chunk >> 3, c8 = (chunk & 7)*8;
    bf16x8 rv = *(const bf16x8*)(fbase + px*64 + c8);
    short4v lo, hi;
    #pragma unroll
    for (int j=0;j<4;j++)
      lo[j] = f2bs(fmaf(bs2f(rv[j]), s_gnA[c8+j], s_gnB[c8+j]));
    #pragma unroll
    for (int j=0;j<4;j++)
      hi[j] = f2bs(fmaf(bs2f(rv[j+4]), s_gnA[c8+4+j], s_gnB[c8+4+j]));
    *(short4v*)&s_xn[px*72 + c8]     = lo;
    *(short4v*)&s_xn[px*72 + c8 + 4] = hi;
  }
  __syncthreads();

  // ---- B-fragments ----
  bf16x8 Bf[2][8];
  #pragma unroll
  for (int kc=0;kc<2;kc++)
    #pragma unroll
    for (int nt=0;nt<8;nt++)
      Bf[kc][nt] = *(const bf16x8*)&s_xn[(nt*16+m)*72 + kc*32 + quad*8];
  __syncthreads();   // s_xn dead; s_kg/s_v writable

  // ---- k & i -> kg ----
  {
    bf16x8 Ak[2], Ai[2];
    #pragma unroll
    for (int kc=0;kc<2;kc++){
      Ak[kc] = *(const bf16x8*)&Wkb[l*4096 + (rowbase+m)*64 + kc*32 + quad*8];
      Ai[kc] = *(const bf16x8*)&Wgb[l*8192 + (64+rowbase+m)*64 + kc*32 + quad*8];
    }
    #pragma unroll
    for (int half=0; half<2; half++){
      f32x4 acck[4], acci[4];
      #pragma unroll
      for (int q4=0;q4<4;q4++){ acck[q4]=z4; acci[q4]=z4; }
      #pragma unroll
      for (int kc=0;kc<2;kc++)
        #pragma unroll
        for (int q4=0;q4<4;q4++){
          acck[q4] = __builtin_amdgcn_mfma_f32_16x16x32_bf16(Ak[kc], Bf[kc][half*4+q4], acck[q4], 0,0,0);
          acci[q4] = __builtin_amdgcn_mfma_f32_16x16x32_bf16(Ai[kc], Bf[kc][half*4+q4], acci[q4], 0,0,0);
        }
      #pragma unroll
      for (int q4=0;q4<4;q4++){
        int nt = half*4+q4;
        #pragma unroll
        for (int r=0;r<4;r++){
          int row = rowbase + quad*4 + r;
          float kv = acck[q4][r] + bkv[r];
          float iv = acci[q4][r] + biv[r];
          s_kg[row*136 + nt*16 + m] = f2bs(kv * sigmoidf_(iv));
        }
      }
    }
  }
  // ---- v ----
  {
    bf16x8 Av[2];
    #pragma unroll
    for (int kc=0;kc<2;kc++)
      Av[kc] = *(const bf16x8*)&Wvb[l*4096 + (rowbase+m)*64 + kc*32 + quad*8];
    #pragma unroll
    for (int half=0; half<2; half++){
      f32x4 accv[4];
      #pragma unroll
      for (int q4=0;q4<4;q4++) accv[q4]=z4;
      #pragma unroll
      for (int kc=0;kc<2;kc++)
        #pragma unroll
        for (int q4=0;q4<4;q4++)
          accv[q4] = __builtin_amdgcn_mfma_f32_16x16x32_bf16(Av[kc], Bf[kc][half*4+q4], accv[q4], 0,0,0);
      #pragma unroll
      for (int q4=0;q4<4;q4++){
        int nt = half*4+q4;
        #pragma unroll
        for (int r=0;r<4;r++){
          int row = rowbase + quad*4 + r;
          s_v[row*136 + nt*16 + m] = f2bs(accv[q4][r] + bvv[r]);
        }
      }
    }
  }
  // ---- f -> fs ----
  {
    bf16x8 Af[2];
    #pragma unroll
    for (int kc=0;kc<2;kc++)
      Af[kc] = *(const bf16x8*)&Wgb[l*8192 + (rowbase+m)*64 + kc*32 + quad*8];
    #pragma unroll
    for (int half=0; half<2; half++){
      f32x4 accf[4];
      #pragma unroll
      for (int q4=0;q4<4;q4++) accf[q4]=z4;
      #pragma unroll
      for (int kc=0;kc<2;kc++)
        #pragma unroll
        for (int q4=0;q4<4;q4++)
          accf[q4] = __builtin_amdgcn_mfma_f32_16x16x32_bf16(Af[kc], Bf[kc][half*4+q4], accf[q4], 0,0,0);
      #pragma unroll
      for (int q4=0;q4<4;q4++)
        #pragma unroll
        for (int r=0;r<4;r++)
          fs[r] += sigmoidf_(accf[q4][r] + bfv[r]);
    }
  }
  __syncthreads();

  // ---- knowledge ----
  #pragma unroll
  for (int kc4=0; kc4<4; kc4++){
    bf16x8 a = *(const bf16x8*)&s_kg[(rowbase + m)*136 + kc4*32 + quad*8];
    #pragma unroll
    for (int dt=0; dt<4; dt++){
      bf16x8 bv8 = *(const bf16x8*)&s_v[(dt*16 + m)*136 + kc4*32 + quad*8];
      accn[dt] = __builtin_amdgcn_mfma_f32_16x16x32_bf16(a, bv8, accn[dt], 0,0,0);
    }
  }

  // ---- f_sum (strided entries) ----
  #pragma unroll
  for (int off=1; off<16; off<<=1)
    #pragma unroll
    for (int r=0;r<4;r++) fs[r] += __shfl_xor(fs[r], off, 64);
  if (m == 0){
    #pragma unroll
    for (int r=0;r<4;r++)
      atomicAdd(&f_sum[(b*64 + rowbase + quad*4 + r)*32], fs[r]);
  }
  // ---- know contribution -> per-block slot (bf16, coalesced stores) ----
  short* kr = kslot + ((size_t)b*NSLOT + blockIdx.x)*4096;
  #pragma unroll
  for (int dt=0;dt<4;dt++)
    #pragma unroll
    for (int r=0;r<4;r++)
      kr[(rowbase + quad*4 + r)*64 + dt*16 + m] = f2bs(accn[dt][r]);
}

// ---------- parallel know-slot reduction + mem update + accumulator re-zero ----------
__global__ __launch_bounds__(256) void k_memreduce(
    const short* __restrict__ kslot, float* __restrict__ f_sum,
    const float* __restrict__ hidden_in, int l,
    float* __restrict__ hidden_out, short* __restrict__ membG,
    float* __restrict__ ssum_next)
{
  int b = blockIdx.y;
  int t = threadIdx.x;
  int e = t & 127;
  int half = t >> 7;
  int cd = blockIdx.x*128 + e;

  const float invN = 1.0f/(float)NPIX;
  // all threads read fmean early (entry owned exclusively by this block)
  float fmean = f_sum[(b*64 + (cd>>6))*32] * invN;

  const short* base = kslot + ((size_t)b*NSLOT + half*256)*4096 + cd;
  float s = 0.f;
  #pragma unroll 16
  for (int sl=0; sl<256; sl++) s += bs2f(base[(size_t)sl*4096]);

  __shared__ float red[128];
  if (half) red[e] = s;
  __syncthreads();
  if (!half){
    float kn = (s + red[e]) * invN;
    float pm = hidden_in[(size_t)(b*NLAYER+l)*4096 + cd];
    float nm = fmean*pm + kn;
    hidden_out[(size_t)(b*NLAYER+l)*4096 + cd] = nm;
    membG[b*4096 + cd] = f2bs(nm);
  } else {
    // re-zero f_sum (after the barrier; all reads happened pre-barrier)
    if ((e & 63) == 0) f_sum[(b*64 + (cd>>6))*32] = 0.f;
  }
  // zero next-layer stat accumulator (before retr's atomics, via kernel boundary)
  if (blockIdx.x == 0 && t < 16) ssum_next[(b*16 + t)*32] = 0.f;
}

// ---------- retrieval+proj+residual with per-block Meff/beff compute ----------
__global__ __launch_bounds__(256,3) void k_retrproj(
    const float* __restrict__ ssum_l,
    const float* __restrict__ gammaP, const float* __restrict__ betaP,
    const short* __restrict__ membG,
    const short* __restrict__ Wpb, const short* __restrict__ Wqtb,
    const float* __restrict__ bqP, const float* __restrict__ bpP,
    int l, short* __restrict__ feat, float* __restrict__ ssum_next)
{
  int b = blockIdx.y;
  int n0 = blockIdx.x * 128;
  int t = threadIdx.x;
  int w = t >> 6;
  int lane = t & 63;
  int m = lane & 15;
  int quad = lane >> 4;

  __shared__ float s_out[128*68];   // 34816 B; phases alias inside
  short* s_memb = (short*)s_out;        // [c][d] stride 72 (4608 shorts)
  short* s_mfb  = (short*)s_out + 4608; // [o][c] stride 72
  short* s_meff = (short*)s_out;        // Meff [o][e] stride 72 (reuses s_memb)
  short* s_xn   = (short*)s_out;        // [px][c] stride 72 (9216 shorts)
  __shared__ float s_gnA[64], s_gnB[64], s_beff[64], s_bq[64];
  __shared__ float s_sacc[16];

  gnCoef(ssum_l, b, t, gammaP, betaP, l, s_gnA, s_gnB);
  if (t < 64) s_bq[t] = bqP[l*64 + t];
  if (t < 16) s_sacc[t] = 0.f;

  // ---- load mem (bf16) into LDS ----
  #pragma unroll
  for (int i=0;i<16;i++){
    int cd = t + i*256;
    int c = cd >> 6, d = cd & 63;
    s_memb[c*72 + d] = membG[b*4096 + cd];
  }
  __syncthreads();

  f32x4 z4 = {0.f,0.f,0.f,0.f};

  // ---- GEMM1: mf[o][c] = sum_d Wp[o][d]*mem[c][d] ----
  bf16x8 Ap[2];
  #pragma unroll
  for (int kc=0;kc<2;kc++)
    Ap[kc] = *(const bf16x8*)&Wpb[l*4096 + (w*16+m)*64 + kc*32 + quad*8];

  float be[4];
  #pragma unroll
  for (int r=0;r<4;r++) be[r] = 0.f;

  #pragma unroll
  for (int ct=0; ct<4; ct++){
    f32x4 a = z4;
    #pragma unroll
    for (int kc=0;kc<2;kc++){
      bf16x8 Bm = *(const bf16x8*)&s_memb[(ct*16+m)*72 + kc*32 + quad*8];
      a = __builtin_amdgcn_mfma_f32_16x16x32_bf16(Ap[kc], Bm, a, 0,0,0);
    }
    int c = ct*16 + m;
    #pragma unroll
    for (int r=0;r<4;r++){
      int o = w*16 + quad*4 + r;
      s_mfb[o*72 + c] = f2bs(a[r]);
      be[r] += a[r] * s_bq[c];
    }
  }
  __syncthreads();

  // ---- GEMM2: Meff[o][e] = 0.125 * sum_c mf[o][c]*WqT[e][c]; write to s_meff ----
  bf16x8 Am2[2];
  #pragma unroll
  for (int kc=0;kc<2;kc++)
    Am2[kc] = *(const bf16x8*)&s_mfb[(w*16+m)*72 + kc*32 + quad*8];
  #pragma unroll
  for (int et=0; et<4; et++){
    f32x4 a = z4;
    #pragma unroll
    for (int kc=0;kc<2;kc++){
      bf16x8 Bq = *(const bf16x8*)&Wqtb[l*4096 + (et*16+m)*64 + kc*32 + quad*8];
      a = __builtin_amdgcn_mfma_f32_16x16x32_bf16(Am2[kc], Bq, a, 0,0,0);
    }
    #pragma unroll
    for (int r=0;r<4;r++){
      int o = w*16 + quad*4 + r;
      s_meff[o*72 + et*16 + m] = f2bs(0.125f*a[r]);
    }
  }
  // beff: reduce over the 16 m-lanes
  #pragma unroll
  for (int off=1; off<16; off<<=1)
    #pragma unroll
    for (int r=0;r<4;r++) be[r] += __shfl_xor(be[r], off, 64);
  if (m == 0){
    #pragma unroll
    for (int r=0;r<4;r++){
      int o = w*16 + quad*4 + r;
      s_beff[o] = bpP[l*64 + o] + 0.125f*be[r];
    }
  }
  __syncthreads();

  // ---- Am fragments from s_meff (own wave's rows) ----
  bf16x8 Am[2];
  #pragma unroll
  for (int kc=0;kc<2;kc++)
    Am[kc] = *(const bf16x8*)&s_meff[(w*16 + m)*72 + kc*32 + quad*8];
  __syncthreads();   // s_meff dead; staging may overwrite

  // ---- stage GN'd tile ----
  short* fbase = feat + ((size_t)b*NPIX + n0)*64;
  #pragma unroll
  for (int i=0;i<4;i++){
    int chunk = t + i*256;
    int px = chunk >> 3, c8 = (chunk & 7)*8;
    bf16x8 rv = *(const bf16x8*)(fbase + px*64 + c8);
    short4v lo, hi;
    #pragma unroll
    for (int j=0;j<4;j++)
      lo[j] = f2bs(fmaf(bs2f(rv[j]), s_gnA[c8+j], s_gnB[c8+j]));
    #pragma unroll
    for (int j=0;j<4;j++)
      hi[j] = f2bs(fmaf(bs2f(rv[j+4]), s_gnA[c8+4+j], s_gnB[c8+4+j]));
    *(short4v*)&s_xn[px*72 + c8]     = lo;
    *(short4v*)&s_xn[px*72 + c8 + 4] = hi;
  }
  __syncthreads();

  bf16x8 Bf[2][8];
  #pragma unroll
  for (int kc=0;kc<2;kc++)
    #pragma unroll
    for (int nt=0;nt<8;nt++)
      Bf[kc][nt] = *(const bf16x8*)&s_xn[(nt*16+m)*72 + kc*32 + quad*8];
  __syncthreads();   // s_xn dead; s_out writable

  f32x4 acc[8];
  #pragma unroll
  for (int nt=0;nt<8;nt++) acc[nt]=z4;
  #pragma unroll
  for (int kc=0;kc<2;kc++)
    #pragma unroll
    for (int nt=0;nt<8;nt++)
      acc[nt] = __builtin_amdgcn_mfma_f32_16x16x32_bf16(Am[kc], Bf[kc][nt], acc[nt], 0,0,0);

  // transpose retrieval output into [px][c]
  #pragma unroll
  for (int nt=0;nt<8;nt++)
    #pragma unroll
    for (int r=0;r<4;r++)
      s_out[(nt*16+m)*68 + w*16 + quad*4 + r] = acc[nt][r];
  __syncthreads();

  // writeback + next-layer GN stats
  float gsv = 0.f, gqv = 0.f;
  int c8 = (t & 7)*8;
  #pragma unroll
  for (int i=0;i<4;i++){
    int chunk = t + i*256;
    int px = chunk >> 3;
    short* fp = fbase + px*64 + c8;
    bf16x8 rv = *(const bf16x8*)fp;
    f32x4 o1 = *(const f32x4*)&s_out[px*68 + c8];
    f32x4 o2 = *(const f32x4*)&s_out[px*68 + c8 + 4];
    short4v r1, r2;
    #pragma unroll
    for (int j=0;j<4;j++){
      float o = bs2f(rv[j]) + o1[j] + s_beff[c8+j];
      r1[j] = f2bs(o);
      gsv += o; gqv += o*o;
    }
    #pragma unroll
    for (int j=0;j<4;j++){
      float o = bs2f(rv[j+4]) + o2[j] + s_beff[c8+4+j];
      r2[j] = f2bs(o);
      gsv += o; gqv += o*o;
    }
    *(short4v*)fp = r1;
    *(short4v*)(fp+4) = r2;
  }
  // reduce the 8 lanes sharing a group (equal lane&7): xor bits 3,4,5
  gsv += __shfl_xor(gsv, 8, 64);  gqv += __shfl_xor(gqv, 8, 64);
  gsv += __shfl_xor(gsv, 16, 64); gqv += __shfl_xor(gqv, 16, 64);
  gsv += __shfl_xor(gsv, 32, 64); gqv += __shfl_xor(gqv, 32, 64);
  if ((lane & 56) == 0){
    int g = lane & 7;
    atomicAdd(&s_sacc[g*2], gsv);
    atomicAdd(&s_sacc[g*2+1], gqv);
  }
  __syncthreads();
  if (t < 16) atomicAdd(&ssum_next[(b*16 + t)*32], s_sacc[t]);
}

// ---------- conv3x3 64->2 + residual; feat [px][c] bf16, weights [o][k][c] ----------
__global__ void k_conv_out(const short* __restrict__ feat, const float* __restrict__ wt,
                           const float* __restrict__ bias,
                           const float* __restrict__ xin, float* __restrict__ out){
  int b = blockIdx.y;
  int y = blockIdx.x;
  int xx = threadIdx.x;
  float acc0 = bias[0], acc1 = bias[1];
  #pragma unroll
  for (int dy=-1; dy<=1; dy++){
    int yy = y + dy;
    if (yy < 0 || yy >= HDIM) continue;
    #pragma unroll
    for (int dx=-1; dx<=1; dx++){
      int xc = xx + dx;
      if (xc >= 0 && xc < HDIM){
        const short* fp = feat + ((size_t)b*NPIX + yy*HDIM + xc)*64;
        const float* w0 = wt + ((0*3 + dy+1)*3 + dx+1)*64;
        const float* w1 = wt + ((1*3 + dy+1)*3 + dx+1)*64;
        #pragma unroll
        for (int c8=0;c8<8;c8++){
          bf16x8 fv = *(const bf16x8*)(fp + c8*8);
          f32x4 w0a = *(const f32x4*)(w0 + c8*8);
          f32x4 w0b = *(const f32x4*)(w0 + c8*8 + 4);
          f32x4 w1a = *(const f32x4*)(w1 + c8*8);
          f32x4 w1b = *(const f32x4*)(w1 + c8*8 + 4);
          #pragma unroll
          for (int j=0;j<4;j++){
            float fa = bs2f(fv[j]), fb2 = bs2f(fv[j+4]);
            acc0 += fa*w0a[j] + fb2*w0b[j];
            acc1 += fa*w1a[j] + fb2*w1b[j];
          }
        }
      }
    }
  }
  size_t p0 = (size_t)(b*2+0)*NPIX + y*HDIM + xx;
  size_t p1 = (size_t)(b*2+1)*NPIX + y*HDIM + xx;
  out[p0] = acc0 + xin[p0];
  out[p1] = acc1 + xin[p1];
}

extern "C" void kernel_launch(void* const* d_in, const int* in_sizes, int n_in,
                              void* d_out, int out_size, void* d_ws, size_t ws_size,
                              hipStream_t stream){
  char* ws = (char*)d_ws;
  short* feat  = (short*)(ws + OFS_FEAT);
  short* kslot = (short*)(ws + OFS_KSLOT);
  short* membg = (short*)(ws + OFS_MEMBG);
  float* fsum  = (float*)(ws + OFS_FSUM);
  float* ssum  = (float*)(ws + OFS_SSUM);   // 2 ping buffers of 1024 floats
  short* wkb   = (short*)(ws + OFS_WKB);
  short* wvb   = (short*)(ws + OFS_WVB);
  short* wgb   = (short*)(ws + OFS_WGB);
  float* wtout = (float*)(ws + OFS_WTOUT);
  short* wpb   = (short*)(ws + OFS_WPB);
  short* wqtb  = (short*)(ws + OFS_WQTB);

  const float* x      = (const float*)d_in[0];
  const float* hidden = (const float*)d_in[1];
  const float* W_in   = (const float*)d_in[2];
  const float* b_in   = (const float*)d_in[3];
  const float* gamma  = (const float*)d_in[4];
  const float* beta   = (const float*)d_in[5];
  const float* Wq     = (const float*)d_in[6];
  const float* bq     = (const float*)d_in[7];
  const float* Wk     = (const float*)d_in[8];
  const float* bk     = (const float*)d_in[9];
  const float* Wv     = (const float*)d_in[10];
  const float* bv     = (const float*)d_in[11];
  const float* Wg     = (const float*)d_in[12];
  const float* bg     = (const float*)d_in[13];
  const float* Wp     = (const float*)d_in[14];
  const float* bp     = (const float*)d_in[15];
  const float* W_out  = (const float*)d_in[16];
  const float* b_out  = (const float*)d_in[17];

  float* out        = (float*)d_out;
  float* hidden_out = out + BATCH*2*NPIX;

  hipMemsetAsync(ws + OFS_FSUM, 0, ZERO_BYTES, stream);
  k_prepw<<<dim3(128), dim3(256), 0, stream>>>(Wk, Wv, Wg, W_out, Wp, Wq,
                                               wkb, wvb, wgb, wtout, wpb, wqtb);
  k_conv_in<<<dim3(HDIM, BATCH), dim3(256), 0, stream>>>(x, W_in, b_in, feat, ssum);

  for (int l=0; l<NLAYER; l++){
    float* ssum_l = ssum + (l & 1)*1024;
    float* ssum_n = ssum + ((l+1) & 1)*1024;
    k_qkvg_know<<<dim3(NPIX/128, BATCH), dim3(256), 0, stream>>>(
        feat, ssum_l, gamma, beta, wkb, bk, wvb, bv, wgb, bg, l, kslot, fsum);
    k_memreduce<<<dim3(32, BATCH), dim3(256), 0, stream>>>(
        kslot, fsum, hidden, l, hidden_out, membg, ssum_n);
    k_retrproj<<<dim3(NPIX/128, BATCH), dim3(256), 0, stream>>>(
        ssum_l, gamma, beta, membg, wpb, wqtb, bq, bp, l, feat, ssum_n);
  }

  k_conv_out<<<dim3(HDIM, BATCH), dim3(256), 0, stream>>>(feat, wtout, b_out, x, out);
}

// Round 12
// 340.011 us; speedup vs baseline: 1.2270x; 1.0952x over previous
//
#include <hip/hip_runtime.h>
#include <hip/hip_bf16.h>

typedef __hip_bfloat16 bf16;
typedef __attribute__((ext_vector_type(8))) short bf16x8;
typedef __attribute__((ext_vector_type(4))) short short4v;
typedef __attribute__((ext_vector_type(4))) float f32x4;

#define BATCH 2
#define CH 64
#define NPIX 65536  // 256*256
#define HDIM 256
#define NLAYER 4
#define NGRP 8
#define NSLOT 512    // per-b know slots (= qkvg blocks per b)

// ---- workspace byte offsets ----
// feat is [b][px][c] (c-minor) bf16
#define OFS_FEAT   0ull          // 16777216 B
#define OFS_KSLOT  16777216ull   // 2 b x 512 slots x 4096 bf16 = 8388608 B
#define OFS_MEMBG  25165824ull   // 16384 B
#define OFS_FSUM   25182208ull   // 16384 B (strided x32)
#define OFS_SSUM   25198592ull   // 16384 B (2 ping x 2048 f)
#define OFS_BEFF   25214976ull   // 512 B
#define OFS_MEFFB  25215488ull   // 16384 B (bf16)
#define OFS_WKB    25231872ull   // 32768 B
#define OFS_WVB    25264640ull   // 32768 B
#define OFS_WGB    25297408ull   // 65536 B
#define OFS_WTOUT  25362944ull   // 4608 B  ([o][k][c] f32)
#define OFS_WPB    25367552ull   // 32768 B (bf16)
#define OFS_WQTB   25400320ull   // 32768 B (bf16, transposed [e][c])
#define ZERO_BYTES 32768         // fsum + ssum (contiguous from OFS_FSUM)

__device__ __forceinline__ float sigmoidf_(float x){ return 1.0f/(1.0f+__expf(-x)); }

// f32 -> bf16 bits, round-to-nearest-even
__device__ __forceinline__ short f2bs(float x){
  unsigned u = __float_as_uint(x);
  u += 0x7fffu + ((u >> 16) & 1u);
  return (short)(u >> 16);
}
// bf16 bits -> f32
__device__ __forceinline__ float bs2f(short x){
  return __uint_as_float(((unsigned)(unsigned short)x) << 16);
}

__device__ __forceinline__ float waveReduce(float v){
  #pragma unroll
  for (int off=32; off; off>>=1) v += __shfl_xor(v, off, 64);
  return v;
}

// ---------- weight pre-convert ----------
__global__ void k_prepw(const float* __restrict__ Wk, const float* __restrict__ Wv,
                        const float* __restrict__ Wg, const float* __restrict__ Wout,
                        const float* __restrict__ Wp, const float* __restrict__ Wq,
                        short* __restrict__ Wkb, short* __restrict__ Wvb,
                        short* __restrict__ Wgb, float* __restrict__ wtout,
                        short* __restrict__ Wpb, short* __restrict__ Wqtb){
  int i = blockIdx.x*256 + threadIdx.x;
  if (i < 16384){
    Wkb[i] = f2bs(Wk[i]);
    Wvb[i] = f2bs(Wv[i]);
    Wpb[i] = f2bs(Wp[i]);
    int l = i >> 12, within = i & 4095;
    int e = within >> 6, c = within & 63;
    Wqtb[i] = f2bs(Wq[l*4096 + c*64 + e]);   // WqT[e][c] = Wq[c][e]
  }
  if (i < 32768) Wgb[i] = f2bs(Wg[i]);
  if (i < 1152){
    int o = i / 576, rem = i % 576;
    int k = rem >> 6, c = rem & 63;
    wtout[(o*9 + k)*64 + c] = Wout[o*576 + c*9 + k];
  }
}

// ---------- per-block group-stat reduction (conv_in); ssum entries strided x32 ----------
__device__ __forceinline__ void blockStats(const float* gs, const float* gq,
                                           float* ssum_b, int t){
  __shared__ float sacc[16];
  if (t < 16) sacc[t] = 0.f;
  __syncthreads();
  #pragma unroll
  for (int g=0; g<NGRP; g++){
    float s  = waveReduce(gs[g]);
    float sq = waveReduce(gq[g]);
    if ((t & 63) == 0){ atomicAdd(&sacc[g*2], s); atomicAdd(&sacc[g*2+1], sq); }
  }
  __syncthreads();
  if (t < 16) atomicAdd(&ssum_b[t*32], sacc[t]);
}

// ---------- conv3x3 2->64 + fused GN stats; feat out [px][c] bf16 ----------
__global__ void k_conv_in(const float* __restrict__ x, const float* __restrict__ w,
                          const float* __restrict__ bias,
                          short* __restrict__ feat, float* __restrict__ ssum){
  int b = blockIdx.y;
  int t = threadIdx.x;
  int n = blockIdx.x*256 + t;
  int y = n >> 8, xx = n & 255;
  float patch[18];
  int idx = 0;
  #pragma unroll
  for (int ci=0; ci<2; ci++)
    #pragma unroll
    for (int dy=-1; dy<=1; dy++)
      #pragma unroll
      for (int dx=-1; dx<=1; dx++){
        int yy = y+dy, xc = xx+dx;
        float v = 0.f;
        if (yy>=0 && yy<HDIM && xc>=0 && xc<HDIM)
          v = x[((b*2+ci)*HDIM + yy)*HDIM + xc];
        patch[idx++] = v;
      }
  float gs[NGRP], gq[NGRP];
  #pragma unroll
  for (int g=0; g<NGRP; g++){ gs[g]=0.f; gq[g]=0.f; }
  short* fb = feat + ((size_t)b*NPIX + n)*64;
  #pragma unroll
  for (int c4=0; c4<16; c4++){
    short4v sv;
    #pragma unroll
    for (int j=0;j<4;j++){
      int o = c4*4 + j;
      float acc = bias[o];
      #pragma unroll
      for (int k=0; k<18; k++) acc += w[o*18+k]*patch[k];
      sv[j] = f2bs(acc);
      gs[o>>3] += acc; gq[o>>3] += acc*acc;
    }
    *(short4v*)(fb + c4*4) = sv;
  }
  blockStats(gs, gq, ssum + b*512, t);
}

// ---------- GN coefficient compute (ssum strided) ----------
__device__ __forceinline__ void gnCoef(const float* __restrict__ ssum_l, int b, int t,
                                       const float* __restrict__ gammaP,
                                       const float* __restrict__ betaP, int l,
                                       float* s_gnA, float* s_gnB){
  if (t < 64){
    int g = t >> 3;
    const float inv = 1.0f/(8.0f*NPIX);
    float s  = ssum_l[(b*16 + g*2)*32];
    float sq = ssum_l[(b*16 + g*2 + 1)*32];
    float mu = s*inv;
    float var = sq*inv - mu*mu;
    float rstd = rsqrtf(var + 1e-5f);
    float A = rstd * gammaP[l*64 + t];
    s_gnA[t] = A;
    s_gnB[t] = betaP[l*64 + t] - mu * A;
  }
}

// ---------- MFMA: GN + k/i/v/f GEMMs + fused knowledge; 128 px per block ----------
__global__ __launch_bounds__(256,3) void k_qkvg_know(
    const short* __restrict__ feat, const float* __restrict__ ssum_l,
    const float* __restrict__ gammaP, const float* __restrict__ betaP,
    const short* __restrict__ Wkb, const float* __restrict__ bkP,
    const short* __restrict__ Wvb, const float* __restrict__ bvP,
    const short* __restrict__ Wgb, const float* __restrict__ bgP,
    int l, short* __restrict__ kslot, float* __restrict__ f_sum)
{
  int b = blockIdx.y;
  int n0 = blockIdx.x * 128;
  int t = threadIdx.x;
  int w = t >> 6;
  int lane = t & 63;
  int m = lane & 15;
  int quad = lane >> 4;
  int rowbase = w*16;

  __shared__ short s_buf[17408];        // 34816 B; s_kg+s_v, aliased by s_xn
  short* s_kg = s_buf;                   // [c][px] stride 136
  short* s_v  = s_buf + 8704;
  short* s_xn = s_buf;                   // [px][c] stride 72 (9216 shorts)
  __shared__ float s_gnA[64], s_gnB[64];

  // ---- T14: issue feat loads FIRST (latency hides under setup below) ----
  const short* fbase = feat + ((size_t)b*NPIX + n0)*64;
  bf16x8 rv[4];
  #pragma unroll
  for (int i=0;i<4;i++){
    int chunk = t + i*256;
    rv[i] = *(const bf16x8*)(fbase + (chunk >> 3)*64 + (chunk & 7)*8);
  }

  gnCoef(ssum_l, b, t, gammaP, betaP, l, s_gnA, s_gnB);

  float bkv[4], biv[4], bvv[4], bfv[4], fs[4];
  #pragma unroll
  for (int r=0;r<4;r++){
    int row = rowbase + quad*4 + r;
    bkv[r] = bkP[l*64 + row];
    biv[r] = bgP[l*128 + 64 + row];
    bvv[r] = bvP[l*64 + row];
    bfv[r] = bgP[l*128 + row];
    fs[r] = 0.f;
  }
  f32x4 z4 = {0.f,0.f,0.f,0.f};
  f32x4 accn[4];
  #pragma unroll
  for (int dt=0;dt<4;dt++) accn[dt] = z4;

  __syncthreads();

  // ---- apply GN to pre-loaded registers, write LDS ----
  #pragma unroll
  for (int i=0;i<4;i++){
    int chunk = t + i*256;
    int px = chunk >> 3, c8 = (chunk & 7)*8;
    short4v lo, hi;
    #pragma unroll
    for (int j=0;j<4;j++)
      lo[j] = f2bs(fmaf(bs2f(rv[i][j]), s_gnA[c8+j], s_gnB[c8+j]));
    #pragma unroll
    for (int j=0;j<4;j++)
      hi[j] = f2bs(fmaf(bs2f(rv[i][j+4]), s_gnA[c8+4+j], s_gnB[c8+4+j]));
    *(short4v*)&s_xn[px*72 + c8]     = lo;
    *(short4v*)&s_xn[px*72 + c8 + 4] = hi;
  }
  __syncthreads();

  // ---- B-fragments ----
  bf16x8 Bf[2][8];
  #pragma unroll
  for (int kc=0;kc<2;kc++)
    #pragma unroll
    for (int nt=0;nt<8;nt++)
      Bf[kc][nt] = *(const bf16x8*)&s_xn[(nt*16+m)*72 + kc*32 + quad*8];
  __syncthreads();   // s_xn dead; s_kg/s_v writable

  // ---- k & i -> kg ----
  {
    bf16x8 Ak[2], Ai[2];
    #pragma unroll
    for (int kc=0;kc<2;kc++){
      Ak[kc] = *(const bf16x8*)&Wkb[l*4096 + (rowbase+m)*64 + kc*32 + quad*8];
      Ai[kc] = *(const bf16x8*)&Wgb[l*8192 + (64+rowbase+m)*64 + kc*32 + quad*8];
    }
    #pragma unroll
    for (int half=0; half<2; half++){
      f32x4 acck[4], acci[4];
      #pragma unroll
      for (int q4=0;q4<4;q4++){ acck[q4]=z4; acci[q4]=z4; }
      __builtin_amdgcn_s_setprio(1);
      #pragma unroll
      for (int kc=0;kc<2;kc++)
        #pragma unroll
        for (int q4=0;q4<4;q4++){
          acck[q4] = __builtin_amdgcn_mfma_f32_16x16x32_bf16(Ak[kc], Bf[kc][half*4+q4], acck[q4], 0,0,0);
          acci[q4] = __builtin_amdgcn_mfma_f32_16x16x32_bf16(Ai[kc], Bf[kc][half*4+q4], acci[q4], 0,0,0);
        }
      __builtin_amdgcn_s_setprio(0);
      #pragma unroll
      for (int q4=0;q4<4;q4++){
        int nt = half*4+q4;
        #pragma unroll
        for (int r=0;r<4;r++){
          int row = rowbase + quad*4 + r;
          float kv = acck[q4][r] + bkv[r];
          float iv = acci[q4][r] + biv[r];
          s_kg[row*136 + nt*16 + m] = f2bs(kv * sigmoidf_(iv));
        }
      }
    }
  }
  // ---- v ----
  {
    bf16x8 Av[2];
    #pragma unroll
    for (int kc=0;kc<2;kc++)
      Av[kc] = *(const bf16x8*)&Wvb[l*4096 + (rowbase+m)*64 + kc*32 + quad*8];
    #pragma unroll
    for (int half=0; half<2; half++){
      f32x4 accv[4];
      #pragma unroll
      for (int q4=0;q4<4;q4++) accv[q4]=z4;
      __builtin_amdgcn_s_setprio(1);
      #pragma unroll
      for (int kc=0;kc<2;kc++)
        #pragma unroll
        for (int q4=0;q4<4;q4++)
          accv[q4] = __builtin_amdgcn_mfma_f32_16x16x32_bf16(Av[kc], Bf[kc][half*4+q4], accv[q4], 0,0,0);
      __builtin_amdgcn_s_setprio(0);
      #pragma unroll
      for (int q4=0;q4<4;q4++){
        int nt = half*4+q4;
        #pragma unroll
        for (int r=0;r<4;r++){
          int row = rowbase + quad*4 + r;
          s_v[row*136 + nt*16 + m] = f2bs(accv[q4][r] + bvv[r]);
        }
      }
    }
  }
  // ---- f -> fs ----
  {
    bf16x8 Af[2];
    #pragma unroll
    for (int kc=0;kc<2;kc++)
      Af[kc] = *(const bf16x8*)&Wgb[l*8192 + (rowbase+m)*64 + kc*32 + quad*8];
    #pragma unroll
    for (int half=0; half<2; half++){
      f32x4 accf[4];
      #pragma unroll
      for (int q4=0;q4<4;q4++) accf[q4]=z4;
      __builtin_amdgcn_s_setprio(1);
      #pragma unroll
      for (int kc=0;kc<2;kc++)
        #pragma unroll
        for (int q4=0;q4<4;q4++)
          accf[q4] = __builtin_amdgcn_mfma_f32_16x16x32_bf16(Af[kc], Bf[kc][half*4+q4], accf[q4], 0,0,0);
      __builtin_amdgcn_s_setprio(0);
      #pragma unroll
      for (int q4=0;q4<4;q4++)
        #pragma unroll
        for (int r=0;r<4;r++)
          fs[r] += sigmoidf_(accf[q4][r] + bfv[r]);
    }
  }
  __syncthreads();

  // ---- knowledge ----
  __builtin_amdgcn_s_setprio(1);
  #pragma unroll
  for (int kc4=0; kc4<4; kc4++){
    bf16x8 a = *(const bf16x8*)&s_kg[(rowbase + m)*136 + kc4*32 + quad*8];
    #pragma unroll
    for (int dt=0; dt<4; dt++){
      bf16x8 bv8 = *(const bf16x8*)&s_v[(dt*16 + m)*136 + kc4*32 + quad*8];
      accn[dt] = __builtin_amdgcn_mfma_f32_16x16x32_bf16(a, bv8, accn[dt], 0,0,0);
    }
  }
  __builtin_amdgcn_s_setprio(0);

  // ---- f_sum (strided entries) ----
  #pragma unroll
  for (int off=1; off<16; off<<=1)
    #pragma unroll
    for (int r=0;r<4;r++) fs[r] += __shfl_xor(fs[r], off, 64);
  if (m == 0){
    #pragma unroll
    for (int r=0;r<4;r++)
      atomicAdd(&f_sum[(b*64 + rowbase + quad*4 + r)*32], fs[r]);
  }
  // ---- know contribution -> per-block slot (bf16, coalesced stores) ----
  short* kr = kslot + ((size_t)b*NSLOT + blockIdx.x)*4096;
  #pragma unroll
  for (int dt=0;dt<4;dt++)
    #pragma unroll
    for (int r=0;r<4;r++)
      kr[(rowbase + quad*4 + r)*64 + dt*16 + m] = f2bs(accn[dt][r]);
}

// ---------- parallel know-slot reduction + mem update; 32 blocks per b ----------
// vectorized: 16 cd-octs x 16 slot-groups; bf16x8 loads (16B/lane)
__global__ __launch_bounds__(256) void k_memreduce(
    const short* __restrict__ kslot, const float* __restrict__ f_sum,
    const float* __restrict__ hidden_in, int l,
    float* __restrict__ hidden_out, short* __restrict__ membG)
{
  int b = blockIdx.y;
  int t = threadIdx.x;
  int oct = t & 15;          // 16 octs of 8 cd
  int sg  = t >> 4;          // 16 slot groups of 32 slots
  int cd0 = blockIdx.x*128 + oct*8;

  const short* base = kslot + ((size_t)b*NSLOT + sg*32)*4096 + cd0;
  float s[8];
  #pragma unroll
  for (int j=0;j<8;j++) s[j]=0.f;
  #pragma unroll 4
  for (int sl=0; sl<32; sl++){
    bf16x8 v = *(const bf16x8*)(base + (size_t)sl*4096);
    #pragma unroll
    for (int j=0;j<8;j++) s[j] += bs2f(v[j]);
  }

  __shared__ float red[16][128];
  #pragma unroll
  for (int j=0;j<8;j++) red[sg][oct*8+j] = s[j];
  __syncthreads();

  if (t < 128){
    float tot = 0.f;
    #pragma unroll
    for (int g=0; g<16; g++) tot += red[g][t];
    const float invN = 1.0f/(float)NPIX;
    int cd = blockIdx.x*128 + t;
    float fmean = f_sum[(b*64 + (cd>>6))*32] * invN;
    float pm = hidden_in[(size_t)(b*NLAYER+l)*4096 + cd];
    float nm = fmean*pm + tot*invN;
    hidden_out[(size_t)(b*NLAYER+l)*4096 + cd] = nm;
    membG[b*4096 + cd] = f2bs(nm);
  }
}

// ---------- Meff(bf16) + beff via MFMA from membG; re-zero accumulators ----------
__global__ __launch_bounds__(256) void k_meff(
    const short* __restrict__ membG, float* __restrict__ f_sum,
    const short* __restrict__ Wpb, const short* __restrict__ Wqtb,
    const float* __restrict__ bqP, const float* __restrict__ bpP,
    int l, short* __restrict__ Meffb, float* __restrict__ beff,
    float* __restrict__ ssum_next)
{
  int b = blockIdx.x;
  int t = threadIdx.x;
  int w = t >> 6;
  int lane = t & 63;
  int m = lane & 15;
  int quad = lane >> 4;

  __shared__ short s_memb[64*72];  // mem[c][d] bf16, stride 72
  __shared__ short s_mfb[64*72];   // mf[o][c] bf16, stride 72
  __shared__ float s_bq[64];

  if (t < 64) s_bq[t] = bqP[l*64 + t];

  // load mem (bf16) into LDS
  #pragma unroll
  for (int i=0;i<16;i++){
    int cd = t + i*256;
    int c = cd >> 6, d = cd & 63;
    s_memb[c*72 + d] = membG[b*4096 + cd];
  }
  __syncthreads();
  if (t < 64) f_sum[(b*64 + t)*32] = 0.f;
  if (t < 16) ssum_next[(b*16 + t)*32] = 0.f;

  f32x4 z4 = {0.f,0.f,0.f,0.f};

  // ---- GEMM1: mf[o][c] = sum_d Wp[o][d]*mem[c][d]; wave w owns rows w*16..+15 ----
  bf16x8 Ap[2];
  #pragma unroll
  for (int kc=0;kc<2;kc++)
    Ap[kc] = *(const bf16x8*)&Wpb[l*4096 + (w*16+m)*64 + kc*32 + quad*8];

  float be[4];
  #pragma unroll
  for (int r=0;r<4;r++) be[r] = 0.f;

  #pragma unroll
  for (int ct=0; ct<4; ct++){
    f32x4 a = z4;
    #pragma unroll
    for (int kc=0;kc<2;kc++){
      bf16x8 Bm = *(const bf16x8*)&s_memb[(ct*16+m)*72 + kc*32 + quad*8];
      a = __builtin_amdgcn_mfma_f32_16x16x32_bf16(Ap[kc], Bm, a, 0,0,0);
    }
    int c = ct*16 + m;
    #pragma unroll
    for (int r=0;r<4;r++){
      int o = w*16 + quad*4 + r;
      s_mfb[o*72 + c] = f2bs(a[r]);
      be[r] += a[r] * s_bq[c];
    }
  }
  // beff: reduce over the 16 m-lanes (cols)
  #pragma unroll
  for (int off=1; off<16; off<<=1)
    #pragma unroll
    for (int r=0;r<4;r++) be[r] += __shfl_xor(be[r], off, 64);
  if (m == 0){
    #pragma unroll
    for (int r=0;r<4;r++){
      int o = w*16 + quad*4 + r;
      beff[b*64 + o] = bpP[l*64 + o] + 0.125f*be[r];
    }
  }
  __syncthreads();

  // ---- GEMM2: Meff[o][e] = 0.125 * sum_c mf[o][c]*WqT[e][c] ----
  bf16x8 Am2[2];
  #pragma unroll
  for (int kc=0;kc<2;kc++)
    Am2[kc] = *(const bf16x8*)&s_mfb[(w*16+m)*72 + kc*32 + quad*8];
  #pragma unroll
  for (int et=0; et<4; et++){
    f32x4 a = z4;
    #pragma unroll
    for (int kc=0;kc<2;kc++){
      bf16x8 Bq = *(const bf16x8*)&Wqtb[l*4096 + (et*16+m)*64 + kc*32 + quad*8];
      a = __builtin_amdgcn_mfma_f32_16x16x32_bf16(Am2[kc], Bq, a, 0,0,0);
    }
    #pragma unroll
    for (int r=0;r<4;r++){
      int o = w*16 + quad*4 + r;
      Meffb[(size_t)b*4096 + o*64 + et*16 + m] = f2bs(0.125f*a[r]);
    }
  }
}

// ---------- retrieval+proj+residual in-place + next-layer GN stats ----------
__global__ __launch_bounds__(256,3) void k_retrproj(
    const float* __restrict__ ssum_l,
    const float* __restrict__ gammaP, const float* __restrict__ betaP,
    const short* __restrict__ Meffb, const float* __restrict__ beff,
    int l, short* __restrict__ feat, float* __restrict__ ssum_next)
{
  int b = blockIdx.y;
  int n0 = blockIdx.x * 128;
  int t = threadIdx.x;
  int w = t >> 6;
  int lane = t & 63;
  int m = lane & 15;
  int quad = lane >> 4;

  __shared__ float s_out[128*68];   // 34816 B; aliased by s_xn during staging
  short* s_xn = (short*)s_out;      // [px][c] stride 72 (18432 B)
  __shared__ float s_gnA[64], s_gnB[64], s_beff[64];
  __shared__ float s_sacc[16];

  // ---- T14: issue feat loads FIRST ----
  short* fbase = feat + ((size_t)b*NPIX + n0)*64;
  bf16x8 rv[4];
  #pragma unroll
  for (int i=0;i<4;i++){
    int chunk = t + i*256;
    rv[i] = *(const bf16x8*)(fbase + (chunk >> 3)*64 + (chunk & 7)*8);
  }

  gnCoef(ssum_l, b, t, gammaP, betaP, l, s_gnA, s_gnB);
  if (t < 64) s_beff[t] = beff[b*64 + t];
  if (t < 16) s_sacc[t] = 0.f;

  bf16x8 Am[2];
  #pragma unroll
  for (int kc=0;kc<2;kc++)
    Am[kc] = *(const bf16x8*)&Meffb[(size_t)b*4096 + (w*16 + m)*64 + kc*32 + quad*8];

  __syncthreads();

  #pragma unroll
  for (int i=0;i<4;i++){
    int chunk = t + i*256;
    int px = chunk >> 3, c8 = (chunk & 7)*8;
    short4v lo, hi;
    #pragma unroll
    for (int j=0;j<4;j++)
      lo[j] = f2bs(fmaf(bs2f(rv[i][j]), s_gnA[c8+j], s_gnB[c8+j]));
    #pragma unroll
    for (int j=0;j<4;j++)
      hi[j] = f2bs(fmaf(bs2f(rv[i][j+4]), s_gnA[c8+4+j], s_gnB[c8+4+j]));
    *(short4v*)&s_xn[px*72 + c8]     = lo;
    *(short4v*)&s_xn[px*72 + c8 + 4] = hi;
  }
  __syncthreads();

  bf16x8 Bf[2][8];
  #pragma unroll
  for (int kc=0;kc<2;kc++)
    #pragma unroll
    for (int nt=0;nt<8;nt++)
      Bf[kc][nt] = *(const bf16x8*)&s_xn[(nt*16+m)*72 + kc*32 + quad*8];
  __syncthreads();   // s_xn dead; s_out writable

  f32x4 acc[8];
  f32x4 z4 = {0.f,0.f,0.f,0.f};
  #pragma unroll
  for (int nt=0;nt<8;nt++) acc[nt]=z4;
  __builtin_amdgcn_s_setprio(1);
  #pragma unroll
  for (int kc=0;kc<2;kc++)
    #pragma unroll
    for (int nt=0;nt<8;nt++)
      acc[nt] = __builtin_amdgcn_mfma_f32_16x16x32_bf16(Am[kc], Bf[kc][nt], acc[nt], 0,0,0);
  __builtin_amdgcn_s_setprio(0);

  // transpose retrieval output into [px][c]
  #pragma unroll
  for (int nt=0;nt<8;nt++)
    #pragma unroll
    for (int r=0;r<4;r++)
      s_out[(nt*16+m)*68 + w*16 + quad*4 + r] = acc[nt][r];
  __syncthreads();

  // writeback (feat re-read is cache-hot) + next-layer GN stats
  float gsv = 0.f, gqv = 0.f;
  int c8 = (t & 7)*8;
  #pragma unroll
  for (int i=0;i<4;i++){
    int chunk = t + i*256;
    int px = chunk >> 3;
    short* fp = fbase + px*64 + c8;
    bf16x8 rv2 = *(const bf16x8*)fp;
    f32x4 o1 = *(const f32x4*)&s_out[px*68 + c8];
    f32x4 o2 = *(const f32x4*)&s_out[px*68 + c8 + 4];
    short4v r1, r2;
    #pragma unroll
    for (int j=0;j<4;j++){
      float o = bs2f(rv2[j]) + o1[j] + s_beff[c8+j];
      r1[j] = f2bs(o);
      gsv += o; gqv += o*o;
    }
    #pragma unroll
    for (int j=0;j<4;j++){
      float o = bs2f(rv2[j+4]) + o2[j] + s_beff[c8+4+j];
      r2[j] = f2bs(o);
      gsv += o; gqv += o*o;
    }
    *(short4v*)fp = r1;
    *(short4v*)(fp+4) = r2;
  }
  // reduce the 8 lanes sharing a group (equal lane&7): xor bits 3,4,5
  gsv += __shfl_xor(gsv, 8, 64);  gqv += __shfl_xor(gqv, 8, 64);
  gsv += __shfl_xor(gsv, 16, 64); gqv += __shfl_xor(gqv, 16, 64);
  gsv += __shfl_xor(gsv, 32, 64); gqv += __shfl_xor(gqv, 32, 64);
  if ((lane & 56) == 0){
    int g = lane & 7;
    atomicAdd(&s_sacc[g*2], gsv);
    atomicAdd(&s_sacc[g*2+1], gqv);
  }
  __syncthreads();
  if (t < 16) atomicAdd(&ssum_next[(b*16 + t)*32], s_sacc[t]);
}

// ---------- conv3x3 64->2 + residual; feat [px][c] bf16, weights [o][k][c] ----------
__global__ void k_conv_out(const short* __restrict__ feat, const float* __restrict__ wt,
                           const float* __restrict__ bias,
                           const float* __restrict__ xin, float* __restrict__ out){
  int b = blockIdx.y;
  int y = blockIdx.x;
  int xx = threadIdx.x;
  float acc0 = bias[0], acc1 = bias[1];
  #pragma unroll
  for (int dy=-1; dy<=1; dy++){
    int yy = y + dy;
    if (yy < 0 || yy >= HDIM) continue;
    #pragma unroll
    for (int dx=-1; dx<=1; dx++){
      int xc = xx + dx;
      if (xc >= 0 && xc < HDIM){
        const short* fp = feat + ((size_t)b*NPIX + yy*HDIM + xc)*64;
        const float* w0 = wt + ((0*3 + dy+1)*3 + dx+1)*64;
        const float* w1 = wt + ((1*3 + dy+1)*3 + dx+1)*64;
        #pragma unroll
        for (int c8=0;c8<8;c8++){
          bf16x8 fv = *(const bf16x8*)(fp + c8*8);
          f32x4 w0a = *(const f32x4*)(w0 + c8*8);
          f32x4 w0b = *(const f32x4*)(w0 + c8*8 + 4);
          f32x4 w1a = *(const f32x4*)(w1 + c8*8);
          f32x4 w1b = *(const f32x4*)(w1 + c8*8 + 4);
          #pragma unroll
          for (int j=0;j<4;j++){
            float fa = bs2f(fv[j]), fb2 = bs2f(fv[j+4]);
            acc0 += fa*w0a[j] + fb2*w0b[j];
            acc1 += fa*w1a[j] + fb2*w1b[j];
          }
        }
      }
    }
  }
  size_t p0 = (size_t)(b*2+0)*NPIX + y*HDIM + xx;
  size_t p1 = (size_t)(b*2+1)*NPIX + y*HDIM + xx;
  out[p0] = acc0 + xin[p0];
  out[p1] = acc1 + xin[p1];
}

extern "C" void kernel_launch(void* const* d_in, const int* in_sizes, int n_in,
                              void* d_out, int out_size, void* d_ws, size_t ws_size,
                              hipStream_t stream){
  char* ws = (char*)d_ws;
  short* feat  = (short*)(ws + OFS_FEAT);
  short* kslot = (short*)(ws + OFS_KSLOT);
  short* membg = (short*)(ws + OFS_MEMBG);
  float* fsum  = (float*)(ws + OFS_FSUM);
  float* ssum  = (float*)(ws + OFS_SSUM);   // 2 ping buffers of 1024 floats
  float* beff  = (float*)(ws + OFS_BEFF);
  short* meffb = (short*)(ws + OFS_MEFFB);
  short* wkb   = (short*)(ws + OFS_WKB);
  short* wvb   = (short*)(ws + OFS_WVB);
  short* wgb   = (short*)(ws + OFS_WGB);
  float* wtout = (float*)(ws + OFS_WTOUT);
  short* wpb   = (short*)(ws + OFS_WPB);
  short* wqtb  = (short*)(ws + OFS_WQTB);

  const float* x      = (const float*)d_in[0];
  const float* hidden = (const float*)d_in[1];
  const float* W_in   = (const float*)d_in[2];
  const float* b_in   = (const float*)d_in[3];
  const float* gamma  = (const float*)d_in[4];
  const float* beta   = (const float*)d_in[5];
  const float* Wq     = (const float*)d_in[6];
  const float* bq     = (const float*)d_in[7];
  const float* Wk     = (const float*)d_in[8];
  const float* bk     = (const float*)d_in[9];
  const float* Wv     = (const float*)d_in[10];
  const float* bv     = (const float*)d_in[11];
  const float* Wg     = (const float*)d_in[12];
  const float* bg     = (const float*)d_in[13];
  const float* Wp     = (const float*)d_in[14];
  const float* bp     = (const float*)d_in[15];
  const float* W_out  = (const float*)d_in[16];
  const float* b_out  = (const float*)d_in[17];

  float* out        = (float*)d_out;
  float* hidden_out = out + BATCH*2*NPIX;

  hipMemsetAsync(ws + OFS_FSUM, 0, ZERO_BYTES, stream);
  k_prepw<<<dim3(128), dim3(256), 0, stream>>>(Wk, Wv, Wg, W_out, Wp, Wq,
                                               wkb, wvb, wgb, wtout, wpb, wqtb);
  k_conv_in<<<dim3(HDIM, BATCH), dim3(256), 0, stream>>>(x, W_in, b_in, feat, ssum);

  for (int l=0; l<NLAYER; l++){
    float* ssum_l = ssum + (l & 1)*1024;
    float* ssum_n = ssum + ((l+1) & 1)*1024;
    k_qkvg_know<<<dim3(NPIX/128, BATCH), dim3(256), 0, stream>>>(
        feat, ssum_l, gamma, beta, wkb, bk, wvb, bv, wgb, bg, l, kslot, fsum);
    k_memreduce<<<dim3(32, BATCH), dim3(256), 0, stream>>>(
        kslot, fsum, hidden, l, hidden_out, membg);
    k_meff<<<dim3(BATCH), dim3(256), 0, stream>>>(
        membg, fsum, wpb, wqtb, bq, bp, l, meffb, beff, ssum_n);
    k_retrproj<<<dim3(NPIX/128, BATCH), dim3(256), 0, stream>>>(
        ssum_l, gamma, beta, meffb, beff, l, feat, ssum_n);
  }

  k_conv_out<<<dim3(HDIM, BATCH), dim3(256), 0, stream>>>(feat, wtout, b_out, x, out);
}

// Round 13
// 329.033 us; speedup vs baseline: 1.2680x; 1.0334x over previous
//
#include <hip/hip_runtime.h>
#include <hip/hip_bf16.h>

typedef __hip_bfloat16 bf16;
typedef __attribute__((ext_vector_type(8))) short bf16x8;
typedef __attribute__((ext_vector_type(4))) short short4v;
typedef __attribute__((ext_vector_type(4))) float f32x4;

#define BATCH 2
#define CH 64
#define NPIX 65536  // 256*256
#define HDIM 256
#define NLAYER 4
#define NGRP 8
#define NSLOT 512    // per-b know slots (= qkvg blocks per b)

// ---- workspace byte offsets ----
// feat is [b][px][c] (c-minor) bf16
#define OFS_FEAT   0ull          // 16777216 B
#define OFS_KSLOT  16777216ull   // 2 b x 512 slots x 4096 bf16 = 8388608 B
#define OFS_MEMBG  25165824ull   // 16384 B
#define OFS_FSUM   25182208ull   // 16384 B (strided x32)
#define OFS_SSUM   25198592ull   // 16384 B (2 ping x 2048 f)
#define OFS_BEFF   25214976ull   // 512 B
#define OFS_MEFFB  25215488ull   // 16384 B (bf16)
#define OFS_WKB    25231872ull   // 32768 B
#define OFS_WVB    25264640ull   // 32768 B
#define OFS_WGB    25297408ull   // 65536 B
#define OFS_WTOUT  25362944ull   // 4608 B  ([o][k][c] f32)
#define OFS_WPB    25367552ull   // 32768 B (bf16)
#define OFS_WQTB   25400320ull   // 32768 B (bf16, transposed [e][c])
#define ZERO_BYTES 32768         // fsum + ssum (contiguous from OFS_FSUM)

__device__ __forceinline__ float sigmoidf_(float x){ return 1.0f/(1.0f+__expf(-x)); }

// f32 -> bf16 bits, round-to-nearest-even
__device__ __forceinline__ short f2bs(float x){
  unsigned u = __float_as_uint(x);
  u += 0x7fffu + ((u >> 16) & 1u);
  return (short)(u >> 16);
}
// bf16 bits -> f32
__device__ __forceinline__ float bs2f(short x){
  return __uint_as_float(((unsigned)(unsigned short)x) << 16);
}

__device__ __forceinline__ float waveReduce(float v){
  #pragma unroll
  for (int off=32; off; off>>=1) v += __shfl_xor(v, off, 64);
  return v;
}

// ---------- weight pre-convert ----------
__global__ void k_prepw(const float* __restrict__ Wk, const float* __restrict__ Wv,
                        const float* __restrict__ Wg, const float* __restrict__ Wout,
                        const float* __restrict__ Wp, const float* __restrict__ Wq,
                        short* __restrict__ Wkb, short* __restrict__ Wvb,
                        short* __restrict__ Wgb, float* __restrict__ wtout,
                        short* __restrict__ Wpb, short* __restrict__ Wqtb){
  int i = blockIdx.x*256 + threadIdx.x;
  if (i < 16384){
    Wkb[i] = f2bs(Wk[i]);
    Wvb[i] = f2bs(Wv[i]);
    Wpb[i] = f2bs(Wp[i]);
    int l = i >> 12, within = i & 4095;
    int e = within >> 6, c = within & 63;
    Wqtb[i] = f2bs(Wq[l*4096 + c*64 + e]);   // WqT[e][c] = Wq[c][e]
  }
  if (i < 32768) Wgb[i] = f2bs(Wg[i]);
  if (i < 1152){
    int o = i / 576, rem = i % 576;
    int k = rem >> 6, c = rem & 63;
    wtout[(o*9 + k)*64 + c] = Wout[o*576 + c*9 + k];
  }
}

// ---------- per-block group-stat reduction (conv_in); ssum entries strided x32 ----------
__device__ __forceinline__ void blockStats(const float* gs, const float* gq,
                                           float* ssum_b, int t){
  __shared__ float sacc[16];
  if (t < 16) sacc[t] = 0.f;
  __syncthreads();
  #pragma unroll
  for (int g=0; g<NGRP; g++){
    float s  = waveReduce(gs[g]);
    float sq = waveReduce(gq[g]);
    if ((t & 63) == 0){ atomicAdd(&sacc[g*2], s); atomicAdd(&sacc[g*2+1], sq); }
  }
  __syncthreads();
  if (t < 16) atomicAdd(&ssum_b[t*32], sacc[t]);
}

// ---------- conv3x3 2->64 + fused GN stats; feat out [px][c] bf16 ----------
__global__ void k_conv_in(const float* __restrict__ x, const float* __restrict__ w,
                          const float* __restrict__ bias,
                          short* __restrict__ feat, float* __restrict__ ssum){
  int b = blockIdx.y;
  int t = threadIdx.x;
  int n = blockIdx.x*256 + t;
  int y = n >> 8, xx = n & 255;
  float patch[18];
  int idx = 0;
  #pragma unroll
  for (int ci=0; ci<2; ci++)
    #pragma unroll
    for (int dy=-1; dy<=1; dy++)
      #pragma unroll
      for (int dx=-1; dx<=1; dx++){
        int yy = y+dy, xc = xx+dx;
        float v = 0.f;
        if (yy>=0 && yy<HDIM && xc>=0 && xc<HDIM)
          v = x[((b*2+ci)*HDIM + yy)*HDIM + xc];
        patch[idx++] = v;
      }
  float gs[NGRP], gq[NGRP];
  #pragma unroll
  for (int g=0; g<NGRP; g++){ gs[g]=0.f; gq[g]=0.f; }
  short* fb = feat + ((size_t)b*NPIX + n)*64;
  #pragma unroll
  for (int c4=0; c4<16; c4++){
    short4v sv;
    #pragma unroll
    for (int j=0;j<4;j++){
      int o = c4*4 + j;
      float acc = bias[o];
      #pragma unroll
      for (int k=0; k<18; k++) acc += w[o*18+k]*patch[k];
      sv[j] = f2bs(acc);
      gs[o>>3] += acc; gq[o>>3] += acc*acc;
    }
    *(short4v*)(fb + c4*4) = sv;
  }
  blockStats(gs, gq, ssum + b*512, t);
}

// ---------- per-thread GN coefficients for own 8 channels (c8 = (t&7)*8) ----------
__device__ __forceinline__ void gnCoefReg(const float* __restrict__ ssum_l, int b, int t,
                                          const float* __restrict__ gammaP,
                                          const float* __restrict__ betaP, int l,
                                          float* gnA, float* gnB){
  const float inv = 1.0f/(8.0f*NPIX);
  int g = t & 7;
  int c8 = g*8;
  float s  = ssum_l[(b*16 + g*2)*32];
  float sq = ssum_l[(b*16 + g*2 + 1)*32];
  float mu = s*inv;
  float rstd = rsqrtf(sq*inv - mu*mu + 1e-5f);
  #pragma unroll
  for (int j=0;j<8;j++){
    gnA[j] = rstd * gammaP[l*64 + c8 + j];
    gnB[j] = betaP[l*64 + c8 + j] - mu * gnA[j];
  }
}

// ---------- MFMA: GN + k/i/v/f GEMMs + fused knowledge; 128 px per block ----------
__global__ __launch_bounds__(256,3) void k_qkvg_know(
    const short* __restrict__ feat, const float* __restrict__ ssum_l,
    const float* __restrict__ gammaP, const float* __restrict__ betaP,
    const short* __restrict__ Wkb, const float* __restrict__ bkP,
    const short* __restrict__ Wvb, const float* __restrict__ bvP,
    const short* __restrict__ Wgb, const float* __restrict__ bgP,
    int l, short* __restrict__ kslot, float* __restrict__ f_sum)
{
  int b = blockIdx.y;
  int n0 = blockIdx.x * 128;
  int t = threadIdx.x;
  int w = t >> 6;
  int lane = t & 63;
  int m = lane & 15;
  int quad = lane >> 4;
  int rowbase = w*16;

  __shared__ short s_buf[17408];        // 34816 B; s_kg+s_v, aliased by s_xn
  short* s_kg = s_buf;                   // [c][px] stride 136
  short* s_v  = s_buf + 8704;
  short* s_xn = s_buf;                   // [px][c] stride 72 (9216 shorts)

  // ---- T14: issue feat loads FIRST (latency hides under setup below) ----
  const short* fbase = feat + ((size_t)b*NPIX + n0)*64;
  bf16x8 rv[4];
  #pragma unroll
  for (int i=0;i<4;i++){
    int chunk = t + i*256;
    rv[i] = *(const bf16x8*)(fbase + (chunk >> 3)*64 + (chunk & 7)*8);
  }

  // ---- per-thread GN coefficients (no LDS, no barrier) ----
  float gnA[8], gnB[8];
  gnCoefReg(ssum_l, b, t, gammaP, betaP, l, gnA, gnB);

  float bkv[4], biv[4], bvv[4], bfv[4], fs[4];
  #pragma unroll
  for (int r=0;r<4;r++){
    int row = rowbase + quad*4 + r;
    bkv[r] = bkP[l*64 + row];
    biv[r] = bgP[l*128 + 64 + row];
    bvv[r] = bvP[l*64 + row];
    bfv[r] = bgP[l*128 + row];
    fs[r] = 0.f;
  }
  f32x4 z4 = {0.f,0.f,0.f,0.f};
  f32x4 accn[4];
  #pragma unroll
  for (int dt=0;dt<4;dt++) accn[dt] = z4;

  // ---- apply GN to pre-loaded registers, write LDS ----
  int c8 = (t & 7)*8;
  #pragma unroll
  for (int i=0;i<4;i++){
    int chunk = t + i*256;
    int px = chunk >> 3;
    short4v lo, hi;
    #pragma unroll
    for (int j=0;j<4;j++)
      lo[j] = f2bs(fmaf(bs2f(rv[i][j]), gnA[j], gnB[j]));
    #pragma unroll
    for (int j=0;j<4;j++)
      hi[j] = f2bs(fmaf(bs2f(rv[i][j+4]), gnA[4+j], gnB[4+j]));
    *(short4v*)&s_xn[px*72 + c8]     = lo;
    *(short4v*)&s_xn[px*72 + c8 + 4] = hi;
  }

  // ---- prefetch first-phase weights (L2 latency hides under barrier+frag reads) ----
  bf16x8 Ak[2], Ai[2];
  #pragma unroll
  for (int kc=0;kc<2;kc++){
    Ak[kc] = *(const bf16x8*)&Wkb[l*4096 + (rowbase+m)*64 + kc*32 + quad*8];
    Ai[kc] = *(const bf16x8*)&Wgb[l*8192 + (64+rowbase+m)*64 + kc*32 + quad*8];
  }
  __syncthreads();

  // ---- B-fragments ----
  bf16x8 Bf[2][8];
  #pragma unroll
  for (int kc=0;kc<2;kc++)
    #pragma unroll
    for (int nt=0;nt<8;nt++)
      Bf[kc][nt] = *(const bf16x8*)&s_xn[(nt*16+m)*72 + kc*32 + quad*8];
  __syncthreads();   // s_xn dead; s_kg/s_v writable

  // ---- k & i -> kg ----
  {
    #pragma unroll
    for (int half=0; half<2; half++){
      f32x4 acck[4], acci[4];
      #pragma unroll
      for (int q4=0;q4<4;q4++){ acck[q4]=z4; acci[q4]=z4; }
      __builtin_amdgcn_s_setprio(1);
      #pragma unroll
      for (int kc=0;kc<2;kc++)
        #pragma unroll
        for (int q4=0;q4<4;q4++){
          acck[q4] = __builtin_amdgcn_mfma_f32_16x16x32_bf16(Ak[kc], Bf[kc][half*4+q4], acck[q4], 0,0,0);
          acci[q4] = __builtin_amdgcn_mfma_f32_16x16x32_bf16(Ai[kc], Bf[kc][half*4+q4], acci[q4], 0,0,0);
        }
      __builtin_amdgcn_s_setprio(0);
      #pragma unroll
      for (int q4=0;q4<4;q4++){
        int nt = half*4+q4;
        #pragma unroll
        for (int r=0;r<4;r++){
          int row = rowbase + quad*4 + r;
          float kv = acck[q4][r] + bkv[r];
          float iv = acci[q4][r] + biv[r];
          s_kg[row*136 + nt*16 + m] = f2bs(kv * sigmoidf_(iv));
        }
      }
    }
  }
  // ---- v ----
  {
    bf16x8 Av[2];
    #pragma unroll
    for (int kc=0;kc<2;kc++)
      Av[kc] = *(const bf16x8*)&Wvb[l*4096 + (rowbase+m)*64 + kc*32 + quad*8];
    #pragma unroll
    for (int half=0; half<2; half++){
      f32x4 accv[4];
      #pragma unroll
      for (int q4=0;q4<4;q4++) accv[q4]=z4;
      __builtin_amdgcn_s_setprio(1);
      #pragma unroll
      for (int kc=0;kc<2;kc++)
        #pragma unroll
        for (int q4=0;q4<4;q4++)
          accv[q4] = __builtin_amdgcn_mfma_f32_16x16x32_bf16(Av[kc], Bf[kc][half*4+q4], accv[q4], 0,0,0);
      __builtin_amdgcn_s_setprio(0);
      #pragma unroll
      for (int q4=0;q4<4;q4++){
        int nt = half*4+q4;
        #pragma unroll
        for (int r=0;r<4;r++){
          int row = rowbase + quad*4 + r;
          s_v[row*136 + nt*16 + m] = f2bs(accv[q4][r] + bvv[r]);
        }
      }
    }
  }
  // ---- f -> fs ----
  {
    bf16x8 Af[2];
    #pragma unroll
    for (int kc=0;kc<2;kc++)
      Af[kc] = *(const bf16x8*)&Wgb[l*8192 + (rowbase+m)*64 + kc*32 + quad*8];
    #pragma unroll
    for (int half=0; half<2; half++){
      f32x4 accf[4];
      #pragma unroll
      for (int q4=0;q4<4;q4++) accf[q4]=z4;
      __builtin_amdgcn_s_setprio(1);
      #pragma unroll
      for (int kc=0;kc<2;kc++)
        #pragma unroll
        for (int q4=0;q4<4;q4++)
          accf[q4] = __builtin_amdgcn_mfma_f32_16x16x32_bf16(Af[kc], Bf[kc][half*4+q4], accf[q4], 0,0,0);
      __builtin_amdgcn_s_setprio(0);
      #pragma unroll
      for (int q4=0;q4<4;q4++)
        #pragma unroll
        for (int r=0;r<4;r++)
          fs[r] += sigmoidf_(accf[q4][r] + bfv[r]);
    }
  }
  __syncthreads();

  // ---- knowledge ----
  __builtin_amdgcn_s_setprio(1);
  #pragma unroll
  for (int kc4=0; kc4<4; kc4++){
    bf16x8 a = *(const bf16x8*)&s_kg[(rowbase + m)*136 + kc4*32 + quad*8];
    #pragma unroll
    for (int dt=0; dt<4; dt++){
      bf16x8 bv8 = *(const bf16x8*)&s_v[(dt*16 + m)*136 + kc4*32 + quad*8];
      accn[dt] = __builtin_amdgcn_mfma_f32_16x16x32_bf16(a, bv8, accn[dt], 0,0,0);
    }
  }
  __builtin_amdgcn_s_setprio(0);

  // ---- f_sum (strided entries) ----
  #pragma unroll
  for (int off=1; off<16; off<<=1)
    #pragma unroll
    for (int r=0;r<4;r++) fs[r] += __shfl_xor(fs[r], off, 64);
  if (m == 0){
    #pragma unroll
    for (int r=0;r<4;r++)
      atomicAdd(&f_sum[(b*64 + rowbase + quad*4 + r)*32], fs[r]);
  }
  // ---- know contribution -> per-block slot (bf16, coalesced stores) ----
  short* kr = kslot + ((size_t)b*NSLOT + blockIdx.x)*4096;
  #pragma unroll
  for (int dt=0;dt<4;dt++)
    #pragma unroll
    for (int r=0;r<4;r++)
      kr[(rowbase + quad*4 + r)*64 + dt*16 + m] = f2bs(accn[dt][r]);
}

// ---------- parallel know-slot reduction + mem update; 32 blocks per b ----------
// vectorized: 16 cd-octs x 16 slot-groups; bf16x8 loads (16B/lane)
__global__ __launch_bounds__(256) void k_memreduce(
    const short* __restrict__ kslot, const float* __restrict__ f_sum,
    const float* __restrict__ hidden_in, int l,
    float* __restrict__ hidden_out, short* __restrict__ membG)
{
  int b = blockIdx.y;
  int t = threadIdx.x;
  int oct = t & 15;          // 16 octs of 8 cd
  int sg  = t >> 4;          // 16 slot groups of 32 slots
  int cd0 = blockIdx.x*128 + oct*8;

  const short* base = kslot + ((size_t)b*NSLOT + sg*32)*4096 + cd0;
  float s[8];
  #pragma unroll
  for (int j=0;j<8;j++) s[j]=0.f;
  #pragma unroll 4
  for (int sl=0; sl<32; sl++){
    bf16x8 v = *(const bf16x8*)(base + (size_t)sl*4096);
    #pragma unroll
    for (int j=0;j<8;j++) s[j] += bs2f(v[j]);
  }

  __shared__ float red[16][128];
  #pragma unroll
  for (int j=0;j<8;j++) red[sg][oct*8+j] = s[j];
  __syncthreads();

  if (t < 128){
    float tot = 0.f;
    #pragma unroll
    for (int g=0; g<16; g++) tot += red[g][t];
    const float invN = 1.0f/(float)NPIX;
    int cd = blockIdx.x*128 + t;
    float fmean = f_sum[(b*64 + (cd>>6))*32] * invN;
    float pm = hidden_in[(size_t)(b*NLAYER+l)*4096 + cd];
    float nm = fmean*pm + tot*invN;
    hidden_out[(size_t)(b*NLAYER+l)*4096 + cd] = nm;
    membG[b*4096 + cd] = f2bs(nm);
  }
}

// ---------- Meff(bf16) + beff via MFMA from membG; re-zero accumulators ----------
__global__ __launch_bounds__(256) void k_meff(
    const short* __restrict__ membG, float* __restrict__ f_sum,
    const short* __restrict__ Wpb, const short* __restrict__ Wqtb,
    const float* __restrict__ bqP, const float* __restrict__ bpP,
    int l, short* __restrict__ Meffb, float* __restrict__ beff,
    float* __restrict__ ssum_next)
{
  int b = blockIdx.x;
  int t = threadIdx.x;
  int w = t >> 6;
  int lane = t & 63;
  int m = lane & 15;
  int quad = lane >> 4;

  __shared__ short s_memb[64*72];  // mem[c][d] bf16, stride 72
  __shared__ short s_mfb[64*72];   // mf[o][c] bf16, stride 72
  __shared__ float s_bq[64];

  if (t < 64) s_bq[t] = bqP[l*64 + t];

  // load mem (bf16) into LDS
  #pragma unroll
  for (int i=0;i<16;i++){
    int cd = t + i*256;
    int c = cd >> 6, d = cd & 63;
    s_memb[c*72 + d] = membG[b*4096 + cd];
  }
  __syncthreads();
  if (t < 64) f_sum[(b*64 + t)*32] = 0.f;
  if (t < 16) ssum_next[(b*16 + t)*32] = 0.f;

  f32x4 z4 = {0.f,0.f,0.f,0.f};

  // ---- GEMM1: mf[o][c] = sum_d Wp[o][d]*mem[c][d]; wave w owns rows w*16..+15 ----
  bf16x8 Ap[2];
  #pragma unroll
  for (int kc=0;kc<2;kc++)
    Ap[kc] = *(const bf16x8*)&Wpb[l*4096 + (w*16+m)*64 + kc*32 + quad*8];

  float be[4];
  #pragma unroll
  for (int r=0;r<4;r++) be[r] = 0.f;

  #pragma unroll
  for (int ct=0; ct<4; ct++){
    f32x4 a = z4;
    #pragma unroll
    for (int kc=0;kc<2;kc++){
      bf16x8 Bm = *(const bf16x8*)&s_memb[(ct*16+m)*72 + kc*32 + quad*8];
      a = __builtin_amdgcn_mfma_f32_16x16x32_bf16(Ap[kc], Bm, a, 0,0,0);
    }
    int c = ct*16 + m;
    #pragma unroll
    for (int r=0;r<4;r++){
      int o = w*16 + quad*4 + r;
      s_mfb[o*72 + c] = f2bs(a[r]);
      be[r] += a[r] * s_bq[c];
    }
  }
  // beff: reduce over the 16 m-lanes (cols)
  #pragma unroll
  for (int off=1; off<16; off<<=1)
    #pragma unroll
    for (int r=0;r<4;r++) be[r] += __shfl_xor(be[r], off, 64);
  if (m == 0){
    #pragma unroll
    for (int r=0;r<4;r++){
      int o = w*16 + quad*4 + r;
      beff[b*64 + o] = bpP[l*64 + o] + 0.125f*be[r];
    }
  }
  __syncthreads();

  // ---- GEMM2: Meff[o][e] = 0.125 * sum_c mf[o][c]*WqT[e][c] ----
  bf16x8 Am2[2];
  #pragma unroll
  for (int kc=0;kc<2;kc++)
    Am2[kc] = *(const bf16x8*)&s_mfb[(w*16+m)*72 + kc*32 + quad*8];
  #pragma unroll
  for (int et=0; et<4; et++){
    f32x4 a = z4;
    #pragma unroll
    for (int kc=0;kc<2;kc++){
      bf16x8 Bq = *(const bf16x8*)&Wqtb[l*4096 + (et*16+m)*64 + kc*32 + quad*8];
      a = __builtin_amdgcn_mfma_f32_16x16x32_bf16(Am2[kc], Bq, a, 0,0,0);
    }
    #pragma unroll
    for (int r=0;r<4;r++){
      int o = w*16 + quad*4 + r;
      Meffb[(size_t)b*4096 + o*64 + et*16 + m] = f2bs(0.125f*a[r]);
    }
  }
}

// ---------- retrieval+proj+residual in-place + next-layer GN stats ----------
__global__ __launch_bounds__(256,3) void k_retrproj(
    const float* __restrict__ ssum_l,
    const float* __restrict__ gammaP, const float* __restrict__ betaP,
    const short* __restrict__ Meffb, const float* __restrict__ beff,
    int l, short* __restrict__ feat, float* __restrict__ ssum_next)
{
  int b = blockIdx.y;
  int n0 = blockIdx.x * 128;
  int t = threadIdx.x;
  int w = t >> 6;
  int lane = t & 63;
  int m = lane & 15;
  int quad = lane >> 4;

  __shared__ float s_out[128*68];   // 34816 B; aliased by s_xn during staging
  short* s_xn = (short*)s_out;      // [px][c] stride 72 (18432 B)
  __shared__ float s_sacc[16];

  // ---- T14: issue feat loads FIRST ----
  short* fbase = feat + ((size_t)b*NPIX + n0)*64;
  bf16x8 rv[4];
  #pragma unroll
  for (int i=0;i<4;i++){
    int chunk = t + i*256;
    rv[i] = *(const bf16x8*)(fbase + (chunk >> 3)*64 + (chunk & 7)*8);
  }

  // ---- per-thread GN coefs + beff in registers ----
  float gnA[8], gnB[8];
  gnCoefReg(ssum_l, b, t, gammaP, betaP, l, gnA, gnB);
  int c8 = (t & 7)*8;
  float bef[8];
  #pragma unroll
  for (int j=0;j<8;j++) bef[j] = beff[b*64 + c8 + j];
  if (t < 16) s_sacc[t] = 0.f;

  bf16x8 Am[2];
  #pragma unroll
  for (int kc=0;kc<2;kc++)
    Am[kc] = *(const bf16x8*)&Meffb[(size_t)b*4096 + (w*16 + m)*64 + kc*32 + quad*8];

  // ---- apply GN, write LDS (no prior barrier needed) ----
  #pragma unroll
  for (int i=0;i<4;i++){
    int chunk = t + i*256;
    int px = chunk >> 3;
    short4v lo, hi;
    #pragma unroll
    for (int j=0;j<4;j++)
      lo[j] = f2bs(fmaf(bs2f(rv[i][j]), gnA[j], gnB[j]));
    #pragma unroll
    for (int j=0;j<4;j++)
      hi[j] = f2bs(fmaf(bs2f(rv[i][j+4]), gnA[4+j], gnB[4+j]));
    *(short4v*)&s_xn[px*72 + c8]     = lo;
    *(short4v*)&s_xn[px*72 + c8 + 4] = hi;
  }
  __syncthreads();

  bf16x8 Bf[2][8];
  #pragma unroll
  for (int kc=0;kc<2;kc++)
    #pragma unroll
    for (int nt=0;nt<8;nt++)
      Bf[kc][nt] = *(const bf16x8*)&s_xn[(nt*16+m)*72 + kc*32 + quad*8];
  __syncthreads();   // s_xn dead; s_out writable

  f32x4 acc[8];
  f32x4 z4 = {0.f,0.f,0.f,0.f};
  #pragma unroll
  for (int nt=0;nt<8;nt++) acc[nt]=z4;
  __builtin_amdgcn_s_setprio(1);
  #pragma unroll
  for (int kc=0;kc<2;kc++)
    #pragma unroll
    for (int nt=0;nt<8;nt++)
      acc[nt] = __builtin_amdgcn_mfma_f32_16x16x32_bf16(Am[kc], Bf[kc][nt], acc[nt], 0,0,0);
  __builtin_amdgcn_s_setprio(0);

  // transpose retrieval output into [px][c]
  #pragma unroll
  for (int nt=0;nt<8;nt++)
    #pragma unroll
    for (int r=0;r<4;r++)
      s_out[(nt*16+m)*68 + w*16 + quad*4 + r] = acc[nt][r];
  __syncthreads();

  // writeback (feat re-read is cache-hot) + next-layer GN stats
  float gsv = 0.f, gqv = 0.f;
  #pragma unroll
  for (int i=0;i<4;i++){
    int chunk = t + i*256;
    int px = chunk >> 3;
    short* fp = fbase + px*64 + c8;
    bf16x8 rv2 = *(const bf16x8*)fp;
    f32x4 o1 = *(const f32x4*)&s_out[px*68 + c8];
    f32x4 o2 = *(const f32x4*)&s_out[px*68 + c8 + 4];
    short4v r1, r2;
    #pragma unroll
    for (int j=0;j<4;j++){
      float o = bs2f(rv2[j]) + o1[j] + bef[j];
      r1[j] = f2bs(o);
      gsv += o; gqv += o*o;
    }
    #pragma unroll
    for (int j=0;j<4;j++){
      float o = bs2f(rv2[j+4]) + o2[j] + bef[4+j];
      r2[j] = f2bs(o);
      gsv += o; gqv += o*o;
    }
    *(short4v*)fp = r1;
    *(short4v*)(fp+4) = r2;
  }
  // reduce the 8 lanes sharing a group (equal lane&7): xor bits 3,4,5
  gsv += __shfl_xor(gsv, 8, 64);  gqv += __shfl_xor(gqv, 8, 64);
  gsv += __shfl_xor(gsv, 16, 64); gqv += __shfl_xor(gqv, 16, 64);
  gsv += __shfl_xor(gsv, 32, 64); gqv += __shfl_xor(gqv, 32, 64);
  if ((lane & 56) == 0){
    int g = lane & 7;
    atomicAdd(&s_sacc[g*2], gsv);
    atomicAdd(&s_sacc[g*2+1], gqv);
  }
  __syncthreads();
  if (t < 16) atomicAdd(&ssum_next[(b*16 + t)*32], s_sacc[t]);
}

// ---------- conv3x3 64->2 + residual; feat [px][c] bf16, weights [o][k][c] ----------
__global__ void k_conv_out(const short* __restrict__ feat, const float* __restrict__ wt,
                           const float* __restrict__ bias,
                           const float* __restrict__ xin, float* __restrict__ out){
  int b = blockIdx.y;
  int y = blockIdx.x;
  int xx = threadIdx.x;
  float acc0 = bias[0], acc1 = bias[1];
  #pragma unroll
  for (int dy=-1; dy<=1; dy++){
    int yy = y + dy;
    if (yy < 0 || yy >= HDIM) continue;
    #pragma unroll
    for (int dx=-1; dx<=1; dx++){
      int xc = xx + dx;
      if (xc >= 0 && xc < HDIM){
        const short* fp = feat + ((size_t)b*NPIX + yy*HDIM + xc)*64;
        const float* w0 = wt + ((0*3 + dy+1)*3 + dx+1)*64;
        const float* w1 = wt + ((1*3 + dy+1)*3 + dx+1)*64;
        #pragma unroll
        for (int c8=0;c8<8;c8++){
          bf16x8 fv = *(const bf16x8*)(fp + c8*8);
          f32x4 w0a = *(const f32x4*)(w0 + c8*8);
          f32x4 w0b = *(const f32x4*)(w0 + c8*8 + 4);
          f32x4 w1a = *(const f32x4*)(w1 + c8*8);
          f32x4 w1b = *(const f32x4*)(w1 + c8*8 + 4);
          #pragma unroll
          for (int j=0;j<4;j++){
            float fa = bs2f(fv[j]), fb2 = bs2f(fv[j+4]);
            acc0 += fa*w0a[j] + fb2*w0b[j];
            acc1 += fa*w1a[j] + fb2*w1b[j];
          }
        }
      }
    }
  }
  size_t p0 = (size_t)(b*2+0)*NPIX + y*HDIM + xx;
  size_t p1 = (size_t)(b*2+1)*NPIX + y*HDIM + xx;
  out[p0] = acc0 + xin[p0];
  out[p1] = acc1 + xin[p1];
}

extern "C" void kernel_launch(void* const* d_in, const int* in_sizes, int n_in,
                              void* d_out, int out_size, void* d_ws, size_t ws_size,
                              hipStream_t stream){
  char* ws = (char*)d_ws;
  short* feat  = (short*)(ws + OFS_FEAT);
  short* kslot = (short*)(ws + OFS_KSLOT);
  short* membg = (short*)(ws + OFS_MEMBG);
  float* fsum  = (float*)(ws + OFS_FSUM);
  float* ssum  = (float*)(ws + OFS_SSUM);   // 2 ping buffers of 1024 floats
  float* beff  = (float*)(ws + OFS_BEFF);
  short* meffb = (short*)(ws + OFS_MEFFB);
  short* wkb   = (short*)(ws + OFS_WKB);
  short* wvb   = (short*)(ws + OFS_WVB);
  short* wgb   = (short*)(ws + OFS_WGB);
  float* wtout = (float*)(ws + OFS_WTOUT);
  short* wpb   = (short*)(ws + OFS_WPB);
  short* wqtb  = (short*)(ws + OFS_WQTB);

  const float* x      = (const float*)d_in[0];
  const float* hidden = (const float*)d_in[1];
  const float* W_in   = (const float*)d_in[2];
  const float* b_in   = (const float*)d_in[3];
  const float* gamma  = (const float*)d_in[4];
  const float* beta   = (const float*)d_in[5];
  const float* Wq     = (const float*)d_in[6];
  const float* bq     = (const float*)d_in[7];
  const float* Wk     = (const float*)d_in[8];
  const float* bk     = (const float*)d_in[9];
  const float* Wv     = (const float*)d_in[10];
  const float* bv     = (const float*)d_in[11];
  const float* Wg     = (const float*)d_in[12];
  const float* bg     = (const float*)d_in[13];
  const float* Wp     = (const float*)d_in[14];
  const float* bp     = (const float*)d_in[15];
  const float* W_out  = (const float*)d_in[16];
  const float* b_out  = (const float*)d_in[17];

  float* out        = (float*)d_out;
  float* hidden_out = out + BATCH*2*NPIX;

  hipMemsetAsync(ws + OFS_FSUM, 0, ZERO_BYTES, stream);
  k_prepw<<<dim3(128), dim3(256), 0, stream>>>(Wk, Wv, Wg, W_out, Wp, Wq,
                                               wkb, wvb, wgb, wtout, wpb, wqtb);
  k_conv_in<<<dim3(HDIM, BATCH), dim3(256), 0, stream>>>(x, W_in, b_in, feat, ssum);

  for (int l=0; l<NLAYER; l++){
    float* ssum_l = ssum + (l & 1)*1024;
    float* ssum_n = ssum + ((l+1) & 1)*1024;
    k_qkvg_know<<<dim3(NPIX/128, BATCH), dim3(256), 0, stream>>>(
        feat, ssum_l, gamma, beta, wkb, bk, wvb, bv, wgb, bg, l, kslot, fsum);
    k_memreduce<<<dim3(32, BATCH), dim3(256), 0, stream>>>(
        kslot, fsum, hidden, l, hidden_out, membg);
    k_meff<<<dim3(BATCH), dim3(256), 0, stream>>>(
        membg, fsum, wpb, wqtb, bq, bp, l, meffb, beff, ssum_n);
    k_retrproj<<<dim3(NPIX/128, BATCH), dim3(256), 0, stream>>>(
        ssum_l, gamma, beta, meffb, beff, l, feat, ssum_n);
  }

  k_conv_out<<<dim3(HDIM, BATCH), dim3(256), 0, stream>>>(feat, wtout, b_out, x, out);
}

// Round 14
// 328.383 us; speedup vs baseline: 1.2705x; 1.0020x over previous
//
#include <hip/hip_runtime.h>
#include <hip/hip_bf16.h>

typedef __hip_bfloat16 bf16;
typedef __attribute__((ext_vector_type(8))) short bf16x8;
typedef __attribute__((ext_vector_type(4))) short short4v;
typedef __attribute__((ext_vector_type(4))) float f32x4;

#define BATCH 2
#define CH 64
#define NPIX 65536  // 256*256
#define HDIM 256
#define NLAYER 4
#define NGRP 8
#define NSLOT 512    // per-b know slots (= qkvg blocks per b)

// ---- workspace byte offsets ----
// feat is [b][px][c] (c-minor) bf16
#define OFS_FEAT   0ull          // 16777216 B
#define OFS_KSLOT  16777216ull   // 2 b x 512 slots x 4096 bf16 = 8388608 B
#define OFS_MEMBG  25165824ull   // 16384 B
#define OFS_FSUM   25182208ull   // 16384 B (strided x32)
#define OFS_SSUM   25198592ull   // 16384 B (2 ping x 2048 f)
#define OFS_BEFF   25214976ull   // 512 B
#define OFS_MEFFB  25215488ull   // 16384 B (bf16)
#define OFS_WKB    25231872ull   // 32768 B
#define OFS_WVB    25264640ull   // 32768 B
#define OFS_WGB    25297408ull   // 65536 B
#define OFS_WTOUT  25362944ull   // 4608 B  ([o][k][c] f32)
#define OFS_WPB    25367552ull   // 32768 B (bf16)
#define OFS_WQTB   25400320ull   // 32768 B (bf16, transposed [e][c])
#define ZERO_BYTES 32768         // fsum + ssum (contiguous from OFS_FSUM)

__device__ __forceinline__ float sigmoidf_(float x){ return 1.0f/(1.0f+__expf(-x)); }

// f32 -> bf16 bits, round-to-nearest-even
__device__ __forceinline__ short f2bs(float x){
  unsigned u = __float_as_uint(x);
  u += 0x7fffu + ((u >> 16) & 1u);
  return (short)(u >> 16);
}
// bf16 bits -> f32
__device__ __forceinline__ float bs2f(short x){
  return __uint_as_float(((unsigned)(unsigned short)x) << 16);
}

__device__ __forceinline__ float waveReduce(float v){
  #pragma unroll
  for (int off=32; off; off>>=1) v += __shfl_xor(v, off, 64);
  return v;
}

// ---------- weight pre-convert ----------
__global__ void k_prepw(const float* __restrict__ Wk, const float* __restrict__ Wv,
                        const float* __restrict__ Wg, const float* __restrict__ Wout,
                        const float* __restrict__ Wp, const float* __restrict__ Wq,
                        short* __restrict__ Wkb, short* __restrict__ Wvb,
                        short* __restrict__ Wgb, float* __restrict__ wtout,
                        short* __restrict__ Wpb, short* __restrict__ Wqtb){
  int i = blockIdx.x*256 + threadIdx.x;
  if (i < 16384){
    Wkb[i] = f2bs(Wk[i]);
    Wvb[i] = f2bs(Wv[i]);
    Wpb[i] = f2bs(Wp[i]);
    int l = i >> 12, within = i & 4095;
    int e = within >> 6, c = within & 63;
    Wqtb[i] = f2bs(Wq[l*4096 + c*64 + e]);   // WqT[e][c] = Wq[c][e]
  }
  if (i < 32768) Wgb[i] = f2bs(Wg[i]);
  if (i < 1152){
    int o = i / 576, rem = i % 576;
    int k = rem >> 6, c = rem & 63;
    wtout[(o*9 + k)*64 + c] = Wout[o*576 + c*9 + k];
  }
}

// ---------- per-block group-stat reduction (conv_in); ssum entries strided x32 ----------
__device__ __forceinline__ void blockStats(const float* gs, const float* gq,
                                           float* ssum_b, int t){
  __shared__ float sacc[16];
  if (t < 16) sacc[t] = 0.f;
  __syncthreads();
  #pragma unroll
  for (int g=0; g<NGRP; g++){
    float s  = waveReduce(gs[g]);
    float sq = waveReduce(gq[g]);
    if ((t & 63) == 0){ atomicAdd(&sacc[g*2], s); atomicAdd(&sacc[g*2+1], sq); }
  }
  __syncthreads();
  if (t < 16) atomicAdd(&ssum_b[t*32], sacc[t]);
}

// ---------- conv3x3 2->64 + fused GN stats; feat out [px][c] bf16 ----------
__global__ void k_conv_in(const float* __restrict__ x, const float* __restrict__ w,
                          const float* __restrict__ bias,
                          short* __restrict__ feat, float* __restrict__ ssum){
  int b = blockIdx.y;
  int t = threadIdx.x;
  int n = blockIdx.x*256 + t;
  int y = n >> 8, xx = n & 255;
  float patch[18];
  int idx = 0;
  #pragma unroll
  for (int ci=0; ci<2; ci++)
    #pragma unroll
    for (int dy=-1; dy<=1; dy++)
      #pragma unroll
      for (int dx=-1; dx<=1; dx++){
        int yy = y+dy, xc = xx+dx;
        float v = 0.f;
        if (yy>=0 && yy<HDIM && xc>=0 && xc<HDIM)
          v = x[((b*2+ci)*HDIM + yy)*HDIM + xc];
        patch[idx++] = v;
      }
  float gs[NGRP], gq[NGRP];
  #pragma unroll
  for (int g=0; g<NGRP; g++){ gs[g]=0.f; gq[g]=0.f; }
  short* fb = feat + ((size_t)b*NPIX + n)*64;
  #pragma unroll
  for (int c4=0; c4<16; c4++){
    short4v sv;
    #pragma unroll
    for (int j=0;j<4;j++){
      int o = c4*4 + j;
      float acc = bias[o];
      #pragma unroll
      for (int k=0; k<18; k++) acc += w[o*18+k]*patch[k];
      sv[j] = f2bs(acc);
      gs[o>>3] += acc; gq[o>>3] += acc*acc;
    }
    *(short4v*)(fb + c4*4) = sv;
  }
  blockStats(gs, gq, ssum + b*512, t);
}

// ---------- per-thread GN coefficients for own 8 channels (c8 = (t&7)*8) ----------
__device__ __forceinline__ void gnCoefReg(const float* __restrict__ ssum_l, int b, int t,
                                          const float* __restrict__ gammaP,
                                          const float* __restrict__ betaP, int l,
                                          float* gnA, float* gnB){
  const float inv = 1.0f/(8.0f*NPIX);
  int g = t & 7;
  int c8 = g*8;
  float s  = ssum_l[(b*16 + g*2)*32];
  float sq = ssum_l[(b*16 + g*2 + 1)*32];
  float mu = s*inv;
  float rstd = rsqrtf(sq*inv - mu*mu + 1e-5f);
  #pragma unroll
  for (int j=0;j<8;j++){
    gnA[j] = rstd * gammaP[l*64 + c8 + j];
    gnB[j] = betaP[l*64 + c8 + j] - mu * gnA[j];
  }
}

// ---------- MFMA: GN + k/i/v/f GEMMs + fused knowledge; 128 px per block ----------
__global__ __launch_bounds__(256,3) void k_qkvg_know(
    const short* __restrict__ feat, const float* __restrict__ ssum_l,
    const float* __restrict__ gammaP, const float* __restrict__ betaP,
    const short* __restrict__ Wkb, const float* __restrict__ bkP,
    const short* __restrict__ Wvb, const float* __restrict__ bvP,
    const short* __restrict__ Wgb, const float* __restrict__ bgP,
    int l, short* __restrict__ kslot, float* __restrict__ f_sum)
{
  int b = blockIdx.y;
  int n0 = blockIdx.x * 128;
  int t = threadIdx.x;
  int w = t >> 6;
  int lane = t & 63;
  int m = lane & 15;
  int quad = lane >> 4;
  int rowbase = w*16;

  __shared__ short s_kgv[17408];        // 34816 B; s_kg + s_v (de-aliased)
  __shared__ short s_xn[9216];          // 18432 B; [px][c] stride 72
  short* s_kg = s_kgv;                   // [c][px] stride 136
  short* s_v  = s_kgv + 8704;

  // ---- T14: issue feat loads FIRST (latency hides under setup below) ----
  const short* fbase = feat + ((size_t)b*NPIX + n0)*64;
  bf16x8 rv[4];
  #pragma unroll
  for (int i=0;i<4;i++){
    int chunk = t + i*256;
    rv[i] = *(const bf16x8*)(fbase + (chunk >> 3)*64 + (chunk & 7)*8);
  }

  // ---- per-thread GN coefficients (no LDS, no barrier) ----
  float gnA[8], gnB[8];
  gnCoefReg(ssum_l, b, t, gammaP, betaP, l, gnA, gnB);

  float bkv[4], biv[4], bvv[4], bfv[4], fs[4];
  #pragma unroll
  for (int r=0;r<4;r++){
    int row = rowbase + quad*4 + r;
    bkv[r] = bkP[l*64 + row];
    biv[r] = bgP[l*128 + 64 + row];
    bvv[r] = bvP[l*64 + row];
    bfv[r] = bgP[l*128 + row];
    fs[r] = 0.f;
  }
  f32x4 z4 = {0.f,0.f,0.f,0.f};
  f32x4 accn[4];
  #pragma unroll
  for (int dt=0;dt<4;dt++) accn[dt] = z4;

  // ---- apply GN to pre-loaded registers, write LDS ----
  int c8 = (t & 7)*8;
  #pragma unroll
  for (int i=0;i<4;i++){
    int chunk = t + i*256;
    int px = chunk >> 3;
    short4v lo, hi;
    #pragma unroll
    for (int j=0;j<4;j++)
      lo[j] = f2bs(fmaf(bs2f(rv[i][j]), gnA[j], gnB[j]));
    #pragma unroll
    for (int j=0;j<4;j++)
      hi[j] = f2bs(fmaf(bs2f(rv[i][j+4]), gnA[4+j], gnB[4+j]));
    *(short4v*)&s_xn[px*72 + c8]     = lo;
    *(short4v*)&s_xn[px*72 + c8 + 4] = hi;
  }

  // ---- prefetch first-phase weights (L2 latency hides under barrier+frag reads) ----
  bf16x8 Ak[2], Ai[2];
  #pragma unroll
  for (int kc=0;kc<2;kc++){
    Ak[kc] = *(const bf16x8*)&Wkb[l*4096 + (rowbase+m)*64 + kc*32 + quad*8];
    Ai[kc] = *(const bf16x8*)&Wgb[l*8192 + (64+rowbase+m)*64 + kc*32 + quad*8];
  }
  __syncthreads();

  // ---- B-fragments (no barrier after: s_kg/s_v are distinct memory) ----
  bf16x8 Bf[2][8];
  #pragma unroll
  for (int kc=0;kc<2;kc++)
    #pragma unroll
    for (int nt=0;nt<8;nt++)
      Bf[kc][nt] = *(const bf16x8*)&s_xn[(nt*16+m)*72 + kc*32 + quad*8];

  // ---- k & i -> kg ----
  {
    #pragma unroll
    for (int half=0; half<2; half++){
      f32x4 acck[4], acci[4];
      #pragma unroll
      for (int q4=0;q4<4;q4++){ acck[q4]=z4; acci[q4]=z4; }
      __builtin_amdgcn_s_setprio(1);
      #pragma unroll
      for (int kc=0;kc<2;kc++)
        #pragma unroll
        for (int q4=0;q4<4;q4++){
          acck[q4] = __builtin_amdgcn_mfma_f32_16x16x32_bf16(Ak[kc], Bf[kc][half*4+q4], acck[q4], 0,0,0);
          acci[q4] = __builtin_amdgcn_mfma_f32_16x16x32_bf16(Ai[kc], Bf[kc][half*4+q4], acci[q4], 0,0,0);
        }
      __builtin_amdgcn_s_setprio(0);
      #pragma unroll
      for (int q4=0;q4<4;q4++){
        int nt = half*4+q4;
        #pragma unroll
        for (int r=0;r<4;r++){
          int row = rowbase + quad*4 + r;
          float kv = acck[q4][r] + bkv[r];
          float iv = acci[q4][r] + biv[r];
          s_kg[row*136 + nt*16 + m] = f2bs(kv * sigmoidf_(iv));
        }
      }
    }
  }
  // ---- v ----
  {
    bf16x8 Av[2];
    #pragma unroll
    for (int kc=0;kc<2;kc++)
      Av[kc] = *(const bf16x8*)&Wvb[l*4096 + (rowbase+m)*64 + kc*32 + quad*8];
    #pragma unroll
    for (int half=0; half<2; half++){
      f32x4 accv[4];
      #pragma unroll
      for (int q4=0;q4<4;q4++) accv[q4]=z4;
      __builtin_amdgcn_s_setprio(1);
      #pragma unroll
      for (int kc=0;kc<2;kc++)
        #pragma unroll
        for (int q4=0;q4<4;q4++)
          accv[q4] = __builtin_amdgcn_mfma_f32_16x16x32_bf16(Av[kc], Bf[kc][half*4+q4], accv[q4], 0,0,0);
      __builtin_amdgcn_s_setprio(0);
      #pragma unroll
      for (int q4=0;q4<4;q4++){
        int nt = half*4+q4;
        #pragma unroll
        for (int r=0;r<4;r++){
          int row = rowbase + quad*4 + r;
          s_v[row*136 + nt*16 + m] = f2bs(accv[q4][r] + bvv[r]);
        }
      }
    }
  }
  // ---- f -> fs ----
  {
    bf16x8 Af[2];
    #pragma unroll
    for (int kc=0;kc<2;kc++)
      Af[kc] = *(const bf16x8*)&Wgb[l*8192 + (rowbase+m)*64 + kc*32 + quad*8];
    #pragma unroll
    for (int half=0; half<2; half++){
      f32x4 accf[4];
      #pragma unroll
      for (int q4=0;q4<4;q4++) accf[q4]=z4;
      __builtin_amdgcn_s_setprio(1);
      #pragma unroll
      for (int kc=0;kc<2;kc++)
        #pragma unroll
        for (int q4=0;q4<4;q4++)
          accf[q4] = __builtin_amdgcn_mfma_f32_16x16x32_bf16(Af[kc], Bf[kc][half*4+q4], accf[q4], 0,0,0);
      __builtin_amdgcn_s_setprio(0);
      #pragma unroll
      for (int q4=0;q4<4;q4++)
        #pragma unroll
        for (int r=0;r<4;r++)
          fs[r] += sigmoidf_(accf[q4][r] + bfv[r]);
    }
  }
  __syncthreads();

  // ---- knowledge ----
  __builtin_amdgcn_s_setprio(1);
  #pragma unroll
  for (int kc4=0; kc4<4; kc4++){
    bf16x8 a = *(const bf16x8*)&s_kg[(rowbase + m)*136 + kc4*32 + quad*8];
    #pragma unroll
    for (int dt=0; dt<4; dt++){
      bf16x8 bv8 = *(const bf16x8*)&s_v[(dt*16 + m)*136 + kc4*32 + quad*8];
      accn[dt] = __builtin_amdgcn_mfma_f32_16x16x32_bf16(a, bv8, accn[dt], 0,0,0);
    }
  }
  __builtin_amdgcn_s_setprio(0);

  // ---- f_sum (strided entries) ----
  #pragma unroll
  for (int off=1; off<16; off<<=1)
    #pragma unroll
    for (int r=0;r<4;r++) fs[r] += __shfl_xor(fs[r], off, 64);
  if (m == 0){
    #pragma unroll
    for (int r=0;r<4;r++)
      atomicAdd(&f_sum[(b*64 + rowbase + quad*4 + r)*32], fs[r]);
  }
  // ---- know contribution -> per-block slot (bf16, coalesced stores) ----
  short* kr = kslot + ((size_t)b*NSLOT + blockIdx.x)*4096;
  #pragma unroll
  for (int dt=0;dt<4;dt++)
    #pragma unroll
    for (int r=0;r<4;r++)
      kr[(rowbase + quad*4 + r)*64 + dt*16 + m] = f2bs(accn[dt][r]);
}

// ---------- parallel know-slot reduction + mem update; 64 blocks per b ----------
// vectorized: 8 cd-octs x 32 slot-groups; bf16x8 loads (16B/lane)
__global__ __launch_bounds__(256) void k_memreduce(
    const short* __restrict__ kslot, const float* __restrict__ f_sum,
    const float* __restrict__ hidden_in, int l,
    float* __restrict__ hidden_out, short* __restrict__ membG)
{
  int b = blockIdx.y;
  int t = threadIdx.x;
  int oct = t & 7;           // 8 octs of 8 cd
  int sg  = t >> 3;          // 32 slot groups of 16 slots
  int cd0 = blockIdx.x*64 + oct*8;

  const short* base = kslot + ((size_t)b*NSLOT + sg*16)*4096 + cd0;
  float s[8];
  #pragma unroll
  for (int j=0;j<8;j++) s[j]=0.f;
  #pragma unroll 4
  for (int sl=0; sl<16; sl++){
    bf16x8 v = *(const bf16x8*)(base + (size_t)sl*4096);
    #pragma unroll
    for (int j=0;j<8;j++) s[j] += bs2f(v[j]);
  }

  __shared__ float red[32][64];
  #pragma unroll
  for (int j=0;j<8;j++) red[sg][oct*8+j] = s[j];
  __syncthreads();

  if (t < 64){
    float tot = 0.f;
    #pragma unroll
    for (int g=0; g<32; g++) tot += red[g][t];
    const float invN = 1.0f/(float)NPIX;
    int cd = blockIdx.x*64 + t;
    float fmean = f_sum[(b*64 + (cd>>6))*32] * invN;
    float pm = hidden_in[(size_t)(b*NLAYER+l)*4096 + cd];
    float nm = fmean*pm + tot*invN;
    hidden_out[(size_t)(b*NLAYER+l)*4096 + cd] = nm;
    membG[b*4096 + cd] = f2bs(nm);
  }
}

// ---------- Meff(bf16) + beff via MFMA from membG; re-zero accumulators ----------
__global__ __launch_bounds__(256) void k_meff(
    const short* __restrict__ membG, float* __restrict__ f_sum,
    const short* __restrict__ Wpb, const short* __restrict__ Wqtb,
    const float* __restrict__ bqP, const float* __restrict__ bpP,
    int l, short* __restrict__ Meffb, float* __restrict__ beff,
    float* __restrict__ ssum_next)
{
  int b = blockIdx.x;
  int t = threadIdx.x;
  int w = t >> 6;
  int lane = t & 63;
  int m = lane & 15;
  int quad = lane >> 4;

  __shared__ short s_memb[64*72];  // mem[c][d] bf16, stride 72
  __shared__ short s_mfb[64*72];   // mf[o][c] bf16, stride 72
  __shared__ float s_bq[64];

  if (t < 64) s_bq[t] = bqP[l*64 + t];

  // load mem (bf16) into LDS
  #pragma unroll
  for (int i=0;i<16;i++){
    int cd = t + i*256;
    int c = cd >> 6, d = cd & 63;
    s_memb[c*72 + d] = membG[b*4096 + cd];
  }
  __syncthreads();
  if (t < 64) f_sum[(b*64 + t)*32] = 0.f;
  if (t < 16) ssum_next[(b*16 + t)*32] = 0.f;

  f32x4 z4 = {0.f,0.f,0.f,0.f};

  // ---- GEMM1: mf[o][c] = sum_d Wp[o][d]*mem[c][d]; wave w owns rows w*16..+15 ----
  bf16x8 Ap[2];
  #pragma unroll
  for (int kc=0;kc<2;kc++)
    Ap[kc] = *(const bf16x8*)&Wpb[l*4096 + (w*16+m)*64 + kc*32 + quad*8];

  float be[4];
  #pragma unroll
  for (int r=0;r<4;r++) be[r] = 0.f;

  #pragma unroll
  for (int ct=0; ct<4; ct++){
    f32x4 a = z4;
    #pragma unroll
    for (int kc=0;kc<2;kc++){
      bf16x8 Bm = *(const bf16x8*)&s_memb[(ct*16+m)*72 + kc*32 + quad*8];
      a = __builtin_amdgcn_mfma_f32_16x16x32_bf16(Ap[kc], Bm, a, 0,0,0);
    }
    int c = ct*16 + m;
    #pragma unroll
    for (int r=0;r<4;r++){
      int o = w*16 + quad*4 + r;
      s_mfb[o*72 + c] = f2bs(a[r]);
      be[r] += a[r] * s_bq[c];
    }
  }
  // beff: reduce over the 16 m-lanes (cols)
  #pragma unroll
  for (int off=1; off<16; off<<=1)
    #pragma unroll
    for (int r=0;r<4;r++) be[r] += __shfl_xor(be[r], off, 64);
  if (m == 0){
    #pragma unroll
    for (int r=0;r<4;r++){
      int o = w*16 + quad*4 + r;
      beff[b*64 + o] = bpP[l*64 + o] + 0.125f*be[r];
    }
  }
  __syncthreads();

  // ---- GEMM2: Meff[o][e] = 0.125 * sum_c mf[o][c]*WqT[e][c] ----
  bf16x8 Am2[2];
  #pragma unroll
  for (int kc=0;kc<2;kc++)
    Am2[kc] = *(const bf16x8*)&s_mfb[(w*16+m)*72 + kc*32 + quad*8];
  #pragma unroll
  for (int et=0; et<4; et++){
    f32x4 a = z4;
    #pragma unroll
    for (int kc=0;kc<2;kc++){
      bf16x8 Bq = *(const bf16x8*)&Wqtb[l*4096 + (et*16+m)*64 + kc*32 + quad*8];
      a = __builtin_amdgcn_mfma_f32_16x16x32_bf16(Am2[kc], Bq, a, 0,0,0);
    }
    #pragma unroll
    for (int r=0;r<4;r++){
      int o = w*16 + quad*4 + r;
      Meffb[(size_t)b*4096 + o*64 + et*16 + m] = f2bs(0.125f*a[r]);
    }
  }
}

// ---------- retrieval+proj+residual in-place + next-layer GN stats ----------
__global__ __launch_bounds__(256,3) void k_retrproj(
    const float* __restrict__ ssum_l,
    const float* __restrict__ gammaP, const float* __restrict__ betaP,
    const short* __restrict__ Meffb, const float* __restrict__ beff,
    int l, short* __restrict__ feat, float* __restrict__ ssum_next)
{
  int b = blockIdx.y;
  int n0 = blockIdx.x * 128;
  int t = threadIdx.x;
  int w = t >> 6;
  int lane = t & 63;
  int m = lane & 15;
  int quad = lane >> 4;

  __shared__ float s_out[128*68];   // 34816 B (de-aliased)
  __shared__ short s_xn[9216];      // 18432 B; [px][c] stride 72
  __shared__ float s_sacc[16];

  // ---- T14: issue feat loads FIRST ----
  short* fbase = feat + ((size_t)b*NPIX + n0)*64;
  bf16x8 rv[4];
  #pragma unroll
  for (int i=0;i<4;i++){
    int chunk = t + i*256;
    rv[i] = *(const bf16x8*)(fbase + (chunk >> 3)*64 + (chunk & 7)*8);
  }

  // ---- per-thread GN coefs + beff in registers ----
  float gnA[8], gnB[8];
  gnCoefReg(ssum_l, b, t, gammaP, betaP, l, gnA, gnB);
  int c8 = (t & 7)*8;
  float bef[8];
  #pragma unroll
  for (int j=0;j<8;j++) bef[j] = beff[b*64 + c8 + j];
  if (t < 16) s_sacc[t] = 0.f;

  bf16x8 Am[2];
  #pragma unroll
  for (int kc=0;kc<2;kc++)
    Am[kc] = *(const bf16x8*)&Meffb[(size_t)b*4096 + (w*16 + m)*64 + kc*32 + quad*8];

  // ---- apply GN, write LDS (no prior barrier needed) ----
  #pragma unroll
  for (int i=0;i<4;i++){
    int chunk = t + i*256;
    int px = chunk >> 3;
    short4v lo, hi;
    #pragma unroll
    for (int j=0;j<4;j++)
      lo[j] = f2bs(fmaf(bs2f(rv[i][j]), gnA[j], gnB[j]));
    #pragma unroll
    for (int j=0;j<4;j++)
      hi[j] = f2bs(fmaf(bs2f(rv[i][j+4]), gnA[4+j], gnB[4+j]));
    *(short4v*)&s_xn[px*72 + c8]     = lo;
    *(short4v*)&s_xn[px*72 + c8 + 4] = hi;
  }
  __syncthreads();

  // ---- B-fragments (no barrier after: s_out is distinct memory) ----
  bf16x8 Bf[2][8];
  #pragma unroll
  for (int kc=0;kc<2;kc++)
    #pragma unroll
    for (int nt=0;nt<8;nt++)
      Bf[kc][nt] = *(const bf16x8*)&s_xn[(nt*16+m)*72 + kc*32 + quad*8];

  f32x4 acc[8];
  f32x4 z4 = {0.f,0.f,0.f,0.f};
  #pragma unroll
  for (int nt=0;nt<8;nt++) acc[nt]=z4;
  __builtin_amdgcn_s_setprio(1);
  #pragma unroll
  for (int kc=0;kc<2;kc++)
    #pragma unroll
    for (int nt=0;nt<8;nt++)
      acc[nt] = __builtin_amdgcn_mfma_f32_16x16x32_bf16(Am[kc], Bf[kc][nt], acc[nt], 0,0,0);
  __builtin_amdgcn_s_setprio(0);

  // transpose retrieval output into [px][c]
  #pragma unroll
  for (int nt=0;nt<8;nt++)
    #pragma unroll
    for (int r=0;r<4;r++)
      s_out[(nt*16+m)*68 + w*16 + quad*4 + r] = acc[nt][r];
  __syncthreads();

  // writeback (feat re-read is cache-hot) + next-layer GN stats
  float gsv = 0.f, gqv = 0.f;
  #pragma unroll
  for (int i=0;i<4;i++){
    int chunk = t + i*256;
    int px = chunk >> 3;
    short* fp = fbase + px*64 + c8;
    bf16x8 rv2 = *(const bf16x8*)fp;
    f32x4 o1 = *(const f32x4*)&s_out[px*68 + c8];
    f32x4 o2 = *(const f32x4*)&s_out[px*68 + c8 + 4];
    short4v r1, r2;
    #pragma unroll
    for (int j=0;j<4;j++){
      float o = bs2f(rv2[j]) + o1[j] + bef[j];
      r1[j] = f2bs(o);
      gsv += o; gqv += o*o;
    }
    #pragma unroll
    for (int j=0;j<4;j++){
      float o = bs2f(rv2[j+4]) + o2[j] + bef[4+j];
      r2[j] = f2bs(o);
      gsv += o; gqv += o*o;
    }
    *(short4v*)fp = r1;
    *(short4v*)(fp+4) = r2;
  }
  // reduce the 8 lanes sharing a group (equal lane&7): xor bits 3,4,5
  gsv += __shfl_xor(gsv, 8, 64);  gqv += __shfl_xor(gqv, 8, 64);
  gsv += __shfl_xor(gsv, 16, 64); gqv += __shfl_xor(gqv, 16, 64);
  gsv += __shfl_xor(gsv, 32, 64); gqv += __shfl_xor(gqv, 32, 64);
  if ((lane & 56) == 0){
    int g = lane & 7;
    atomicAdd(&s_sacc[g*2], gsv);
    atomicAdd(&s_sacc[g*2+1], gqv);
  }
  __syncthreads();
  if (t < 16) atomicAdd(&ssum_next[(b*16 + t)*32], s_sacc[t]);
}

// ---------- conv3x3 64->2 + residual; feat [px][c] bf16, weights [o][k][c] ----------
__global__ void k_conv_out(const short* __restrict__ feat, const float* __restrict__ wt,
                           const float* __restrict__ bias,
                           const float* __restrict__ xin, float* __restrict__ out){
  int b = blockIdx.y;
  int y = blockIdx.x;
  int xx = threadIdx.x;
  float acc0 = bias[0], acc1 = bias[1];
  #pragma unroll
  for (int dy=-1; dy<=1; dy++){
    int yy = y + dy;
    if (yy < 0 || yy >= HDIM) continue;
    #pragma unroll
    for (int dx=-1; dx<=1; dx++){
      int xc = xx + dx;
      if (xc >= 0 && xc < HDIM){
        const short* fp = feat + ((size_t)b*NPIX + yy*HDIM + xc)*64;
        const float* w0 = wt + ((0*3 + dy+1)*3 + dx+1)*64;
        const float* w1 = wt + ((1*3 + dy+1)*3 + dx+1)*64;
        #pragma unroll
        for (int c8=0;c8<8;c8++){
          bf16x8 fv = *(const bf16x8*)(fp + c8*8);
          f32x4 w0a = *(const f32x4*)(w0 + c8*8);
          f32x4 w0b = *(const f32x4*)(w0 + c8*8 + 4);
          f32x4 w1a = *(const f32x4*)(w1 + c8*8);
          f32x4 w1b = *(const f32x4*)(w1 + c8*8 + 4);
          #pragma unroll
          for (int j=0;j<4;j++){
            float fa = bs2f(fv[j]), fb2 = bs2f(fv[j+4]);
            acc0 += fa*w0a[j] + fb2*w0b[j];
            acc1 += fa*w1a[j] + fb2*w1b[j];
          }
        }
      }
    }
  }
  size_t p0 = (size_t)(b*2+0)*NPIX + y*HDIM + xx;
  size_t p1 = (size_t)(b*2+1)*NPIX + y*HDIM + xx;
  out[p0] = acc0 + xin[p0];
  out[p1] = acc1 + xin[p1];
}

extern "C" void kernel_launch(void* const* d_in, const int* in_sizes, int n_in,
                              void* d_out, int out_size, void* d_ws, size_t ws_size,
                              hipStream_t stream){
  char* ws = (char*)d_ws;
  short* feat  = (short*)(ws + OFS_FEAT);
  short* kslot = (short*)(ws + OFS_KSLOT);
  short* membg = (short*)(ws + OFS_MEMBG);
  float* fsum  = (float*)(ws + OFS_FSUM);
  float* ssum  = (float*)(ws + OFS_SSUM);   // 2 ping buffers of 1024 floats
  float* beff  = (float*)(ws + OFS_BEFF);
  short* meffb = (short*)(ws + OFS_MEFFB);
  short* wkb   = (short*)(ws + OFS_WKB);
  short* wvb   = (short*)(ws + OFS_WVB);
  short* wgb   = (short*)(ws + OFS_WGB);
  float* wtout = (float*)(ws + OFS_WTOUT);
  short* wpb   = (short*)(ws + OFS_WPB);
  short* wqtb  = (short*)(ws + OFS_WQTB);

  const float* x      = (const float*)d_in[0];
  const float* hidden = (const float*)d_in[1];
  const float* W_in   = (const float*)d_in[2];
  const float* b_in   = (const float*)d_in[3];
  const float* gamma  = (const float*)d_in[4];
  const float* beta   = (const float*)d_in[5];
  const float* Wq     = (const float*)d_in[6];
  const float* bq     = (const float*)d_in[7];
  const float* Wk     = (const float*)d_in[8];
  const float* bk     = (const float*)d_in[9];
  const float* Wv     = (const float*)d_in[10];
  const float* bv     = (const float*)d_in[11];
  const float* Wg     = (const float*)d_in[12];
  const float* bg     = (const float*)d_in[13];
  const float* Wp     = (const float*)d_in[14];
  const float* bp     = (const float*)d_in[15];
  const float* W_out  = (const float*)d_in[16];
  const float* b_out  = (const float*)d_in[17];

  float* out        = (float*)d_out;
  float* hidden_out = out + BATCH*2*NPIX;

  hipMemsetAsync(ws + OFS_FSUM, 0, ZERO_BYTES, stream);
  k_prepw<<<dim3(128), dim3(256), 0, stream>>>(Wk, Wv, Wg, W_out, Wp, Wq,
                                               wkb, wvb, wgb, wtout, wpb, wqtb);
  k_conv_in<<<dim3(HDIM, BATCH), dim3(256), 0, stream>>>(x, W_in, b_in, feat, ssum);

  for (int l=0; l<NLAYER; l++){
    float* ssum_l = ssum + (l & 1)*1024;
    float* ssum_n = ssum + ((l+1) & 1)*1024;
    k_qkvg_know<<<dim3(NPIX/128, BATCH), dim3(256), 0, stream>>>(
        feat, ssum_l, gamma, beta, wkb, bk, wvb, bv, wgb, bg, l, kslot, fsum);
    k_memreduce<<<dim3(64, BATCH), dim3(256), 0, stream>>>(
        kslot, fsum, hidden, l, hidden_out, membg);
    k_meff<<<dim3(BATCH), dim3(256), 0, stream>>>(
        membg, fsum, wpb, wqtb, bq, bp, l, meffb, beff, ssum_n);
    k_retrproj<<<dim3(NPIX/128, BATCH), dim3(256), 0, stream>>>(
        ssum_l, gamma, beta, meffb, beff, l, feat, ssum_n);
  }

  k_conv_out<<<dim3(HDIM, BATCH), dim3(256), 0, stream>>>(feat, wtout, b_out, x, out);
}